// Round 5
// baseline (655.560 us; speedup 1.0000x reference)
//
#include <hip/hip_runtime.h>

// InfiniAttention — Round 15: mega-kernel with SOFTWARE grid barrier (no cooperative
// launch — hipLaunchCooperativeKernel is the prime suspect for the R14 container hang
// under hipGraph capture, and for the R12/R13 tail-store anomaly). Plain <<<512,256>>>
// launch; 4 per-phase atomic arrival counters in ws, zeroed by hipMemsetAsync each call.
// __launch_bounds__(256,2) guarantees 512-block co-residency (proven by R12/R13 coop
// capacity validation). Phases identical to R14; kF is the R11-proven regular kernel.

#define HIDDEN 1024
#define DMEM 256
#define BATCH 4
#define SEQ 1024
#define MTOT (BATCH * SEQ)      // 4096
#define CHUNK 128
#define NCH (SEQ / CHUNK)       // 8
#define NCHT (BATCH * NCH)      // 32
#define EPSF 1e-6f
#define NBLK 512u

typedef __bf16 bf16x8 __attribute__((ext_vector_type(8)));
typedef __bf16 bf16x4 __attribute__((ext_vector_type(4)));
typedef float f32x4 __attribute__((ext_vector_type(4)));

#define GL_LDS(g, l)                                                                   \
  __builtin_amdgcn_global_load_lds((const __attribute__((address_space(1))) void*)(g), \
                                   (__attribute__((address_space(3))) void*)(l), 16, 0, 0)

__device__ __forceinline__ float elu1(float x) { return x > 0.f ? x + 1.f : __expf(x); }

// Software grid barrier: one counter per phase. All 512 blocks co-resident
// (launch_bounds(256,2)) so spin cannot deadlock. __syncthreads drains vmcnt(0)
// per wave before s_barrier; release-RMW at agent scope publishes (L2 wb);
// acquire spin + trailing threadfence invalidates stale caches.
__device__ __forceinline__ void gridbar(unsigned* bar, int phase) {
  __syncthreads();
  if (threadIdx.x == 0) {
    __hip_atomic_fetch_add(&bar[phase], 1u, __ATOMIC_RELEASE, __HIP_MEMORY_SCOPE_AGENT);
    while (__hip_atomic_load(&bar[phase], __ATOMIC_ACQUIRE, __HIP_MEMORY_SCOPE_AGENT) <
           NBLK) {
      __builtin_amdgcn_s_sleep(2);
    }
  }
  __syncthreads();
  __threadfence();
}

// Stage a 128-row x 64-col tile as two 32-col slabs (slab h at sm + h*4096).
__device__ __forceinline__ void stage128(const __bf16* p, long ld, int k0, __bf16* sm,
                                         int wave) {
  GL_LDS(p + k0, sm + wave * 512);
  GL_LDS(p + (size_t)64 * ld + k0, sm + 2048 + wave * 512);
  GL_LDS(p + k0 + 32, sm + 4096 + wave * 512);
  GL_LDS(p + (size_t)64 * ld + k0 + 32, sm + 4096 + 2048 + wave * 512);
}
// Stage a 64-row x 64-col tile as two slabs (slab h at sm + h*2048).
__device__ __forceinline__ void stage64(const __bf16* p, int k0, __bf16* sm, int wave) {
  GL_LDS(p + k0, sm + wave * 512);
  GL_LDS(p + k0 + 32, sm + 2048 + wave * 512);
}

// 128x128 tile, BK=64.
__device__ __forceinline__ void gemm128_bk64(const __bf16* aptr, long lda, const __bf16* bptr,
                                             long ldb, int klen, __bf16* smA, __bf16* smB,
                                             int wave, int wr, int wc, int quad, int l16,
                                             f32x4 (&acc)[4][4]) {
  for (int k0 = 0; k0 < klen; k0 += 64) {
    stage128(aptr, lda, k0, smA, wave);
    stage128(bptr, ldb, k0, smB, wave);
    __syncthreads();
#pragma unroll
    for (int h = 0; h < 2; ++h) {
      bf16x8 aF[4], bF[4];
#pragma unroll
      for (int i = 0; i < 4; ++i)
        aF[i] = *reinterpret_cast<const bf16x8*>(smA + h * 4096 +
                                                 (wr * 64 + i * 16 + l16) * 32 + quad * 8);
#pragma unroll
      for (int j = 0; j < 4; ++j)
        bF[j] = *reinterpret_cast<const bf16x8*>(smB + h * 4096 +
                                                 (wc * 64 + j * 16 + l16) * 32 + quad * 8);
#pragma unroll
      for (int i = 0; i < 4; ++i)
#pragma unroll
        for (int j = 0; j < 4; ++j)
          acc[i][j] = __builtin_amdgcn_mfma_f32_16x16x32_bf16(aF[i], bF[j], acc[i][j], 0, 0, 0);
    }
    __syncthreads();
  }
}

// 64x128 tile, BK=64.
__device__ __forceinline__ void gemm64_bk64(const __bf16* aptr, const __bf16* bptr, long ldb,
                                            int klen, __bf16* smA, __bf16* smB, int wave,
                                            int wr, int wc, int quad, int l16,
                                            f32x4 (&acc)[2][4]) {
  for (int k0 = 0; k0 < klen; k0 += 64) {
    stage64(aptr, k0, smA, wave);
    stage128(bptr, ldb, k0, smB, wave);
    __syncthreads();
#pragma unroll
    for (int h = 0; h < 2; ++h) {
      bf16x8 aF[2], bF[4];
#pragma unroll
      for (int i = 0; i < 2; ++i)
        aF[i] = *reinterpret_cast<const bf16x8*>(smA + h * 2048 +
                                                 (wr * 32 + i * 16 + l16) * 32 + quad * 8);
#pragma unroll
      for (int j = 0; j < 4; ++j)
        bF[j] = *reinterpret_cast<const bf16x8*>(smB + h * 4096 +
                                                 (wc * 64 + j * 16 + l16) * 32 + quad * 8);
#pragma unroll
      for (int i = 0; i < 2; ++i)
#pragma unroll
        for (int j = 0; j < 4; ++j)
          acc[i][j] = __builtin_amdgcn_mfma_f32_16x16x32_bf16(aF[i], bF[j], acc[i][j], 0, 0, 0);
    }
    __syncthreads();
  }
}

__global__ __launch_bounds__(256, 2) void mega(
    const float* __restrict__ hs, const float* __restrict__ wq, const float* __restrict__ wk,
    const float* __restrict__ wv, const float* __restrict__ wo, const float* __restrict__ gate,
    const float* __restrict__ mem, const float* __restrict__ mnorm, float* __restrict__ out,
    float* __restrict__ ksc, float* __restrict__ den, float* __restrict__ qn,
    float* __restrict__ kn, __bf16* __restrict__ kvcT, __bf16* __restrict__ hsb,
    __bf16* __restrict__ wqkvb, __bf16* __restrict__ wob, __bf16* __restrict__ memT,
    __bf16* __restrict__ sqb, __bf16* __restrict__ skb, __bf16* __restrict__ skT,
    __bf16* __restrict__ vT, __bf16* __restrict__ scb, __bf16* __restrict__ kvpT,
    __bf16* __restrict__ combb, __bf16* __restrict__ dvT, unsigned* bar) {
  __shared__ __bf16 smem[20480];  // 40 KB pool, carved per phase
  __shared__ float warr[4];
  int bid = blockIdx.x;
  int tid = threadIdx.x;
  int lane = tid & 63, wave = tid >> 6;
  int wr = wave >> 1, wc = wave & 1, quad = lane >> 4, l16 = lane & 15;

  // ---------------- P0: hs cast (bid<256) + wqkv cast (256..303) ----------------
  if (bid < 256) {
#pragma unroll
    for (int it = 0; it < 16; ++it) {
      int i = bid * 4096 + it * 256 + tid;
      float4 f = reinterpret_cast<const float4*>(hs)[i];
      bf16x4 h = {(__bf16)f.x, (__bf16)f.y, (__bf16)f.z, (__bf16)f.w};
      reinterpret_cast<bf16x4*>(hsb)[i] = h;
    }
  } else if (bid < 304) {
    int t = bid - 256;  // 0..47
    int mat = t >> 4;   // 0..2
    const float* src = (mat == 0) ? wq : (mat == 1) ? wk : wv;
    __bf16* dst = wqkvb + (size_t)mat * (DMEM * HIDDEN);
#pragma unroll
    for (int it = 0; it < 16; ++it) {
      int i = (t & 15) * 4096 + it * 256 + tid;
      float4 f = reinterpret_cast<const float4*>(src)[i];
      bf16x4 h = {(__bf16)f.x, (__bf16)f.y, (__bf16)f.z, (__bf16)f.w};
      reinterpret_cast<bf16x4*>(dst)[i] = h;
    }
  }
  gridbar(bar, 0);

  // P1: QKV GEMM (bid<384) + wo cast (384..399) + memT (400..415) + full seed (416..431)
  if (bid < 384) {
    int m0 = (bid & 63) * 64;
    int by = bid >> 6;  // 0..5
    int wsel = by >> 1, n0 = (by & 1) * 128;
    const __bf16* aptr = hsb + (size_t)(m0 + (tid >> 2)) * HIDDEN + ((tid & 3) << 3);
    const __bf16* bptr = wqkvb + (size_t)(by * 128 + (tid >> 2)) * HIDDEN + ((tid & 3) << 3);
    f32x4 acc[2][4] = {};
    gemm64_bk64(aptr, bptr, HIDDEN, HIDDEN, smem, smem + 8192, wave, wr, wc, quad, l16, acc);
#pragma unroll
    for (int i = 0; i < 2; ++i)
#pragma unroll
      for (int j = 0; j < 4; ++j) {
        int mb = m0 + wr * 32 + i * 16 + quad * 4;
        int n = n0 + wc * 64 + j * 16 + l16;
        if (wsel == 0) {
#pragma unroll
          for (int r = 0; r < 4; ++r)
            sqb[(size_t)(mb + r) * DMEM + n] = (__bf16)elu1(acc[i][j][r]);
        } else if (wsel == 1) {
          bf16x4 t;
#pragma unroll
          for (int r = 0; r < 4; ++r) {
            float v = elu1(acc[i][j][r]);
            skb[(size_t)(mb + r) * DMEM + n] = (__bf16)v;
            t[r] = (__bf16)v;
          }
          *reinterpret_cast<bf16x4*>(skT + (size_t)n * MTOT + mb) = t;
        } else {
          bf16x4 t;
#pragma unroll
          for (int r = 0; r < 4; ++r) t[r] = (__bf16)acc[i][j][r];
          *reinterpret_cast<bf16x4*>(vT + (size_t)n * MTOT + mb) = t;
        }
      }
  } else if (bid < 400) {
    int t = bid - 384;
#pragma unroll
    for (int it = 0; it < 16; ++it) {
      int i = t * 4096 + it * 256 + tid;
      float4 f = reinterpret_cast<const float4*>(wo)[i];
      bf16x4 h = {(__bf16)f.x, (__bf16)f.y, (__bf16)f.z, (__bf16)f.w};
      reinterpret_cast<bf16x4*>(wob)[i] = h;
    }
  } else if (bid < 416) {
    int t = bid - 400;
    int bx = t & 3, by = t >> 2;
    float* sf = reinterpret_cast<float*>(smem);  // [64][65]
    int r0 = tid >> 6, col = tid & 63;
#pragma unroll
    for (int it = 0; it < 16; ++it) {
      int row = it * 4 + r0;
      sf[row * 65 + col] = mem[(size_t)(by * 64 + row) * DMEM + bx * 64 + col];
    }
    __syncthreads();
#pragma unroll
    for (int it = 0; it < 16; ++it) {
      int row = it * 4 + r0;
      memT[(size_t)(bx * 64 + row) * DMEM + by * 64 + col] = (__bf16)sf[col * 65 + row];
    }
  } else if (bid < 432) {  // full new_memory seed: 16 blocks x 4 iters x 256 thr x float4
    int t = bid - 416;
#pragma unroll
    for (int it = 0; it < 4; ++it) {
      int g = t * 1024 + it * 256 + tid;
      reinterpret_cast<float4*>(out + (size_t)MTOT * HIDDEN)[g] =
          reinterpret_cast<const float4*>(mem)[g];
    }
  }
  gridbar(bar, 1);

  // ---- P2: chunk-KV/scores/ksum (bid<352) + qn/kn rows (352..511) ----
  if (bid < 352) {
    int c = bid & 31, y = bid >> 5;  // y in [0,11)
    if (y == 10) {
      int d = tid;
      float s = 0.f;
      for (int i = 0; i < CHUNK; ++i) s += (float)skb[(size_t)(c * CHUNK + i) * DMEM + d];
      ksc[c * DMEM + d] = s;
    } else if (y < 8) {  // kvcT 64x128 tiles
      int e0 = (y >> 1) * 64, d0 = (y & 1) * 128;
      const __bf16* aptr = vT + (size_t)(e0 + (tid >> 2)) * MTOT + c * CHUNK + ((tid & 3) << 3);
      const __bf16* bptr = skT + (size_t)(d0 + (tid >> 2)) * MTOT + c * CHUNK + ((tid & 3) << 3);
      f32x4 acc[2][4] = {};
      gemm64_bk64(aptr, bptr, MTOT, CHUNK, smem, smem + 8192, wave, wr, wc, quad, l16, acc);
#pragma unroll
      for (int i = 0; i < 2; ++i)
#pragma unroll
        for (int j = 0; j < 4; ++j)
#pragma unroll
          for (int r = 0; r < 4; ++r) {
            int e = e0 + wr * 32 + i * 16 + quad * 4 + r;
            int d = d0 + wc * 64 + j * 16 + l16;
            kvcT[(size_t)c * DMEM * DMEM + (size_t)e * DMEM + d] = (__bf16)acc[i][j][r];
          }
    } else {  // causal scores, i0 = (y-8)*64
      int i0 = (y - 8) * 64;
      const __bf16* aptr =
          sqb + (size_t)(c * CHUNK + i0 + (tid >> 2)) * DMEM + ((tid & 3) << 3);
      const __bf16* bptr = skb + (size_t)(c * CHUNK + (tid >> 2)) * DMEM + ((tid & 3) << 3);
      f32x4 acc[2][4] = {};
      gemm64_bk64(aptr, bptr, DMEM, DMEM, smem, smem + 8192, wave, wr, wc, quad, l16, acc);
#pragma unroll
      for (int i = 0; i < 2; ++i)
#pragma unroll
        for (int j = 0; j < 4; ++j)
#pragma unroll
          for (int r = 0; r < 4; ++r) {
            int ii = i0 + wr * 32 + i * 16 + quad * 4 + r;
            int jj = wc * 64 + j * 16 + l16;
            scb[(size_t)c * CHUNK * CHUNK + (size_t)ii * CHUNK + jj] =
                (jj <= ii) ? (__bf16)acc[i][j][r] : (__bf16)0.f;
          }
    }
  } else {  // qn/kn: 640 waves, rows strided
    int wid = (bid - 352) * 4 + wave;  // [0,640)
    for (int m = wid; m < MTOT; m += 640) {
      float s_qn = 0.f, s_kn = 0.f;
      for (int d = lane; d < DMEM; d += 64) {
        float q = (float)sqb[(size_t)m * DMEM + d];
        float k = (float)skb[(size_t)m * DMEM + d];
        float mn = mnorm[d];
        s_qn += q * mn;
        s_kn += k * mn;
      }
#pragma unroll
      for (int off = 32; off > 0; off >>= 1) {
        s_qn += __shfl_down(s_qn, off);
        s_kn += __shfl_down(s_kn, off);
      }
      if (lane == 0) {
        qn[m] = s_qn;
        kn[m] = s_kn;
      }
    }
  }
  gridbar(bar, 2);

  // ---- P3: kvp prefix (bid<128) + den rows (128..383) + dv (384..511) ----
  if (bid < 128) {
    int batch = bid >> 5;
    size_t idx8 = (size_t)(((bid & 31) * 256 + tid)) * 8;
    float run[8] = {};
    for (int c = 0; c < NCH; ++c) {
      size_t off = (size_t)(batch * NCH + c) * DMEM * DMEM + idx8;
      bf16x8 t = *reinterpret_cast<const bf16x8*>(kvcT + off);
      bf16x8 o;
#pragma unroll
      for (int r = 0; r < 8; ++r) o[r] = (__bf16)run[r];
      *reinterpret_cast<bf16x8*>(kvpT + off) = o;
#pragma unroll
      for (int r = 0; r < 8; ++r) run[r] += (float)t[r];
    }
  } else if (bid < 384) {  // den: 1024 waves x 4 rows
    int wid = (bid - 128) * 4 + wave;  // [0,1024)
    for (int m = wid; m < MTOT; m += 1024) {
      int c = m >> 7, i = m & 127, cb = c & ~7;
      float s_sc = 0.f, s_d2 = 0.f;
      for (int j = lane; j < CHUNK; j += 64)
        s_sc += (float)scb[(size_t)c * CHUNK * CHUNK + (size_t)i * CHUNK + j];
      for (int d = lane; d < DMEM; d += 64) {
        float q = (float)sqb[(size_t)m * DMEM + d];
        float kp = 0.f;
        for (int cc = cb; cc < c; ++cc) kp += ksc[cc * DMEM + d];
        s_d2 += q * kp;
      }
#pragma unroll
      for (int off = 32; off > 0; off >>= 1) {
        s_sc += __shfl_down(s_sc, off);
        s_d2 += __shfl_down(s_d2, off);
      }
      if (lane == 0) den[m] = s_sc + s_d2;
    }
  } else {  // dv = v - (sk@memT)/kn -> dvT, 64x128 tiles
    int t = bid - 384;
    int m0 = (t >> 1) * 64, n0 = (t & 1) * 128;
    const __bf16* aptr = skb + (size_t)(m0 + (tid >> 2)) * DMEM + ((tid & 3) << 3);
    const __bf16* bptr = memT + (size_t)(n0 + (tid >> 2)) * DMEM + ((tid & 3) << 3);
    f32x4 acc[2][4] = {};
    gemm64_bk64(aptr, bptr, DMEM, DMEM, smem, smem + 8192, wave, wr, wc, quad, l16, acc);
#pragma unroll
    for (int i = 0; i < 2; ++i) {
      int mb = m0 + wr * 32 + i * 16 + quad * 4;
      float kv[4];
#pragma unroll
      for (int r = 0; r < 4; ++r) kv[r] = fmaxf(kn[mb + r], EPSF);
#pragma unroll
      for (int j = 0; j < 4; ++j) {
        int n = n0 + wc * 64 + j * 16 + l16;
        bf16x4 vv = *reinterpret_cast<const bf16x4*>(vT + (size_t)n * MTOT + mb);
        bf16x4 tt;
#pragma unroll
        for (int r = 0; r < 4; ++r) tt[r] = (__bf16)((float)vv[r] - acc[i][j][r] / kv[r]);
        *reinterpret_cast<bf16x4*>(dvT + (size_t)n * MTOT + mb) = tt;
      }
    }
  }
  gridbar(bar, 3);

  // ---- P4: combine only (bid<128) ----
  if (bid < 128) {
    float mv = mnorm[tid];
#pragma unroll
    for (int off = 32; off > 0; off >>= 1) mv += __shfl_down(mv, off);
    if (lane == 0) warr[wave] = mv;
    __syncthreads();
    float fl = ((warr[0] + warr[1] + warr[2] + warr[3]) < EPSF) ? 0.f : 1.f;
    __syncthreads();
    int c = bid >> 2, yy = bid & 3;
    int i0 = (yy >> 1) * 64, e0 = (yy & 1) * 128;
    f32x4 acc_loc[2][4] = {};
    f32x4 acc_mem[2][4] = {};
    {  // phase 1: scores @ v (K=128)
      const __bf16* aptr =
          scb + (size_t)c * CHUNK * CHUNK + (size_t)(i0 + (tid >> 2)) * CHUNK + ((tid & 3) << 3);
      const __bf16* bptr = vT + (size_t)(e0 + (tid >> 2)) * MTOT + c * CHUNK + ((tid & 3) << 3);
      gemm64_bk64(aptr, bptr, MTOT, CHUNK, smem, smem + 4096, wave, wr, wc, quad, l16, acc_loc);
    }
    {  // phase 2: sq @ kvp + sq @ memT (K=256, dual B)
      const __bf16* aptr = sqb + (size_t)(c * CHUNK + i0 + (tid >> 2)) * DMEM + ((tid & 3) << 3);
      const __bf16* b1ptr =
          kvpT + (size_t)c * DMEM * DMEM + (size_t)(e0 + (tid >> 2)) * DMEM + ((tid & 3) << 3);
      const __bf16* b2ptr = memT + (size_t)(e0 + (tid >> 2)) * DMEM + ((tid & 3) << 3);
      __bf16* As = smem;
      __bf16* B1s = smem + 4096;
      __bf16* B2s = smem + 12288;
      for (int k0 = 0; k0 < DMEM; k0 += 64) {
        stage64(aptr, k0, As, wave);
        stage128(b1ptr, DMEM, k0, B1s, wave);
        stage128(b2ptr, DMEM, k0, B2s, wave);
        __syncthreads();
#pragma unroll
        for (int h = 0; h < 2; ++h) {
          bf16x8 aF[2], b1F[4], b2F[4];
#pragma unroll
          for (int i = 0; i < 2; ++i)
            aF[i] = *reinterpret_cast<const bf16x8*>(As + h * 2048 +
                                                     (wr * 32 + i * 16 + l16) * 32 + quad * 8);
#pragma unroll
          for (int j = 0; j < 4; ++j) {
            b1F[j] = *reinterpret_cast<const bf16x8*>(B1s + h * 4096 +
                                                      (wc * 64 + j * 16 + l16) * 32 + quad * 8);
            b2F[j] = *reinterpret_cast<const bf16x8*>(B2s + h * 4096 +
                                                      (wc * 64 + j * 16 + l16) * 32 + quad * 8);
          }
#pragma unroll
          for (int i = 0; i < 2; ++i)
#pragma unroll
            for (int j = 0; j < 4; ++j) {
              acc_loc[i][j] =
                  __builtin_amdgcn_mfma_f32_16x16x32_bf16(aF[i], b1F[j], acc_loc[i][j], 0, 0, 0);
              acc_mem[i][j] =
                  __builtin_amdgcn_mfma_f32_16x16x32_bf16(aF[i], b2F[j], acc_mem[i][j], 0, 0, 0);
            }
        }
        __syncthreads();
      }
    }
    float g = 1.f / (1.f + __expf(-gate[0]));
#pragma unroll
    for (int i = 0; i < 2; ++i) {
      int mb = c * CHUNK + i0 + wr * 32 + i * 16 + quad * 4;
      float dn[4], qv[4];
#pragma unroll
      for (int r = 0; r < 4; ++r) {
        dn[r] = fmaxf(den[mb + r], EPSF);
        qv[r] = fmaxf(qn[mb + r], EPSF);
      }
#pragma unroll
      for (int j = 0; j < 4; ++j) {
        int e = e0 + wc * 64 + j * 16 + l16;
#pragma unroll
        for (int r = 0; r < 4; ++r) {
          float comb = g * fl * acc_mem[i][j][r] / qv[r] + (1.f - g) * acc_loc[i][j][r] / dn[r];
          combb[(size_t)(mb + r) * DMEM + e] = (__bf16)comb;
        }
      }
    }
  }
}

// -- kF: EXACT R11 code. out-proj (bid<256) + mem-update split-K atomics (256..383)
//    + norm from ksc (384). grid 385 --
__global__ __launch_bounds__(256) void kF(const __bf16* __restrict__ combb,
                                          const __bf16* __restrict__ wob,
                                          const __bf16* __restrict__ skT,
                                          const __bf16* __restrict__ dvT,
                                          const float* __restrict__ ksc,
                                          const float* __restrict__ mnorm,
                                          float* __restrict__ out) {
  __shared__ __bf16 As[8192];
  __shared__ __bf16 Bs[8192];
  int tid = threadIdx.x;
  int bid = blockIdx.x;
  if (bid == 384) {  // new_memory_norm
    int d = tid;
    float s = 0.f;
    for (int c = 0; c < NCHT; ++c) s += ksc[c * DMEM + d];
    out[(size_t)MTOT * HIDDEN + DMEM * DMEM + d] = mnorm[d] + s * (1.f / (float)BATCH);
    return;
  }
  int lane = tid & 63, wave = tid >> 6;
  int wr = wave >> 1, wc = wave & 1, quad = lane >> 4, l16 = lane & 15;
  if (bid < 256) {  // output projection, 128x128 BK=64
    int m0 = (bid & 31) * 128, by = bid >> 5;
    const __bf16* aptr = combb + (size_t)(m0 + (tid >> 2)) * DMEM + ((tid & 3) << 3);
    const __bf16* bptr = wob + (size_t)(by * 128 + (tid >> 2)) * DMEM + ((tid & 3) << 3);
    f32x4 acc[4][4] = {};
    gemm128_bk64(aptr, DMEM, bptr, DMEM, DMEM, As, Bs, wave, wr, wc, quad, l16, acc);
#pragma unroll
    for (int i = 0; i < 4; ++i)
#pragma unroll
      for (int j = 0; j < 4; ++j)
#pragma unroll
        for (int r = 0; r < 4; ++r) {
          int m = m0 + wr * 64 + i * 16 + quad * 4 + r;
          int n = by * 128 + wc * 64 + j * 16 + l16;
          out[(size_t)m * HIDDEN + n] = acc[i][j][r];
        }
  } else {  // mem-update: 16-way split-K (K=256 each), 64x128 tiles, atomics
    int t = bid - 256;
    int kbase = (t >> 3) * 256;
    int yy = t & 7;
    int d0 = (yy >> 1) * 64, e0 = (yy & 1) * 128;
    const __bf16* aptr = skT + (size_t)(d0 + (tid >> 2)) * MTOT + kbase + ((tid & 3) << 3);
    const __bf16* bptr = dvT + (size_t)(e0 + (tid >> 2)) * MTOT + kbase + ((tid & 3) << 3);
    f32x4 acc[2][4] = {};
    gemm64_bk64(aptr, bptr, MTOT, 256, As, Bs, wave, wr, wc, quad, l16, acc);
    float* base = out + (size_t)MTOT * HIDDEN;
#pragma unroll
    for (int i = 0; i < 2; ++i)
#pragma unroll
      for (int j = 0; j < 4; ++j)
#pragma unroll
        for (int r = 0; r < 4; ++r) {
          int d = d0 + wr * 32 + i * 16 + quad * 4 + r;
          int e = e0 + wc * 64 + j * 16 + l16;
          atomicAdd(&base[(size_t)d * DMEM + e], acc[i][j][r] * (1.f / (float)MTOT));
        }
  }
}

extern "C" void kernel_launch(void* const* d_in, const int* in_sizes, int n_in,
                              void* d_out, int out_size, void* d_ws, size_t ws_size,
                              hipStream_t stream) {
  const float* hs = (const float*)d_in[0];
  const float* wq = (const float*)d_in[1];
  const float* wk = (const float*)d_in[2];
  const float* wv = (const float*)d_in[3];
  const float* wo = (const float*)d_in[4];
  const float* gate = (const float*)d_in[5];
  const float* mem = (const float*)d_in[6];
  const float* mnorm = (const float*)d_in[7];
  float* out = (float*)d_out;
  float* ws = (float*)d_ws;

  // fp32 region
  float* ksc = ws;          // 8192
  float* den = ksc + 8192;  // 4096
  float* qn = den + 4096;   // 4096
  float* kn = qn + 4096;    // 4096 (end 20480 floats)
  // bf16 region
  __bf16* kvcT = (__bf16*)(ws + 20480);               // 2097152
  __bf16* hsb = kvcT + (size_t)NCHT * DMEM * DMEM;    // 4194304
  __bf16* wqkvb = hsb + (size_t)MTOT * HIDDEN;        // 786432
  __bf16* wob = wqkvb + (size_t)3 * DMEM * HIDDEN;    // 262144
  __bf16* memT = wob + (size_t)HIDDEN * DMEM;         // 65536
  __bf16* sqb = memT + (size_t)DMEM * DMEM;           // 1048576
  __bf16* skb = sqb + (size_t)MTOT * DMEM;            // 1048576
  __bf16* skT = skb + (size_t)MTOT * DMEM;            // 1048576
  __bf16* vT = skT + (size_t)MTOT * DMEM;             // 1048576
  __bf16* scb = vT + (size_t)MTOT * DMEM;             // 524288
  __bf16* kvpT = scb + (size_t)NCHT * CHUNK * CHUNK;  // 2097152
  __bf16* combb = kvpT + (size_t)NCHT * DMEM * DMEM;  // 1048576
  __bf16* dvT = combb + (size_t)MTOT * DMEM;          // 1048576
  unsigned* bar = (unsigned*)(dvT + (size_t)MTOT * DMEM);  // 4 barrier counters

  hipMemsetAsync(bar, 0, 4 * sizeof(unsigned), stream);
  mega<<<dim3(512), 256, 0, stream>>>(hs, wq, wk, wv, wo, gate, mem, mnorm, out, ksc, den,
                                      qn, kn, kvcT, hsb, wqkvb, wob, memT, sqb, skb, skT,
                                      vT, scb, kvpT, combb, dvT, bar);
  kF<<<dim3(385), 256, 0, stream>>>(combb, wob, skT, dvT, ksc, mnorm, out);
}

// Round 6
// 403.295 us; speedup vs baseline: 1.6255x; 1.6255x over previous
//
#include <hip/hip_runtime.h>

// InfiniAttention — Round 16: R15 with the barrier spin fixed. R15's spin polled with
// ACQUIRE at agent scope => buffer_inv (full L2 invalidate) EVERY POLL from 512 blocks
// => ~125us/barrier invalidate storm (mega 592us @ 0.6% MfmaUtil). Now: arrive with
// RELEASE fetch_add (one wbl2), spin RELAXED (no invalidate), s_sleep(16) backoff,
// ONE acquire __threadfence() after exit. Everything else identical to R15.

#define HIDDEN 1024
#define DMEM 256
#define BATCH 4
#define SEQ 1024
#define MTOT (BATCH * SEQ)      // 4096
#define CHUNK 128
#define NCH (SEQ / CHUNK)       // 8
#define NCHT (BATCH * NCH)      // 32
#define EPSF 1e-6f
#define NBLK 512u

typedef __bf16 bf16x8 __attribute__((ext_vector_type(8)));
typedef __bf16 bf16x4 __attribute__((ext_vector_type(4)));
typedef float f32x4 __attribute__((ext_vector_type(4)));

#define GL_LDS(g, l)                                                                   \
  __builtin_amdgcn_global_load_lds((const __attribute__((address_space(1))) void*)(g), \
                                   (__attribute__((address_space(3))) void*)(l), 16, 0, 0)

__device__ __forceinline__ float elu1(float x) { return x > 0.f ? x + 1.f : __expf(x); }

// Software grid barrier. Arrive: RELEASE fetch_add (one buffer_wbl2 publishes this
// block's phase writes past its non-coherent XCD L2). Spin: RELAXED load — plain
// coherence-point read, NO per-poll invalidate (R15's bug). Exit: one __threadfence
// acquire so this block sees other XCDs' published writes.
__device__ __forceinline__ void gridbar(unsigned* bar, int phase) {
  __syncthreads();
  if (threadIdx.x == 0) {
    __hip_atomic_fetch_add(&bar[phase], 1u, __ATOMIC_RELEASE, __HIP_MEMORY_SCOPE_AGENT);
    while (__hip_atomic_load(&bar[phase], __ATOMIC_RELAXED, __HIP_MEMORY_SCOPE_AGENT) <
           NBLK) {
      __builtin_amdgcn_s_sleep(16);
    }
  }
  __syncthreads();
  __threadfence();
}

// Stage a 128-row x 64-col tile as two 32-col slabs (slab h at sm + h*4096).
__device__ __forceinline__ void stage128(const __bf16* p, long ld, int k0, __bf16* sm,
                                         int wave) {
  GL_LDS(p + k0, sm + wave * 512);
  GL_LDS(p + (size_t)64 * ld + k0, sm + 2048 + wave * 512);
  GL_LDS(p + k0 + 32, sm + 4096 + wave * 512);
  GL_LDS(p + (size_t)64 * ld + k0 + 32, sm + 4096 + 2048 + wave * 512);
}
// Stage a 64-row x 64-col tile as two slabs (slab h at sm + h*2048).
__device__ __forceinline__ void stage64(const __bf16* p, int k0, __bf16* sm, int wave) {
  GL_LDS(p + k0, sm + wave * 512);
  GL_LDS(p + k0 + 32, sm + 2048 + wave * 512);
}

// 128x128 tile, BK=64.
__device__ __forceinline__ void gemm128_bk64(const __bf16* aptr, long lda, const __bf16* bptr,
                                             long ldb, int klen, __bf16* smA, __bf16* smB,
                                             int wave, int wr, int wc, int quad, int l16,
                                             f32x4 (&acc)[4][4]) {
  for (int k0 = 0; k0 < klen; k0 += 64) {
    stage128(aptr, lda, k0, smA, wave);
    stage128(bptr, ldb, k0, smB, wave);
    __syncthreads();
#pragma unroll
    for (int h = 0; h < 2; ++h) {
      bf16x8 aF[4], bF[4];
#pragma unroll
      for (int i = 0; i < 4; ++i)
        aF[i] = *reinterpret_cast<const bf16x8*>(smA + h * 4096 +
                                                 (wr * 64 + i * 16 + l16) * 32 + quad * 8);
#pragma unroll
      for (int j = 0; j < 4; ++j)
        bF[j] = *reinterpret_cast<const bf16x8*>(smB + h * 4096 +
                                                 (wc * 64 + j * 16 + l16) * 32 + quad * 8);
#pragma unroll
      for (int i = 0; i < 4; ++i)
#pragma unroll
        for (int j = 0; j < 4; ++j)
          acc[i][j] = __builtin_amdgcn_mfma_f32_16x16x32_bf16(aF[i], bF[j], acc[i][j], 0, 0, 0);
    }
    __syncthreads();
  }
}

// 64x128 tile, BK=64.
__device__ __forceinline__ void gemm64_bk64(const __bf16* aptr, const __bf16* bptr, long ldb,
                                            int klen, __bf16* smA, __bf16* smB, int wave,
                                            int wr, int wc, int quad, int l16,
                                            f32x4 (&acc)[2][4]) {
  for (int k0 = 0; k0 < klen; k0 += 64) {
    stage64(aptr, k0, smA, wave);
    stage128(bptr, ldb, k0, smB, wave);
    __syncthreads();
#pragma unroll
    for (int h = 0; h < 2; ++h) {
      bf16x8 aF[2], bF[4];
#pragma unroll
      for (int i = 0; i < 2; ++i)
        aF[i] = *reinterpret_cast<const bf16x8*>(smA + h * 2048 +
                                                 (wr * 32 + i * 16 + l16) * 32 + quad * 8);
#pragma unroll
      for (int j = 0; j < 4; ++j)
        bF[j] = *reinterpret_cast<const bf16x8*>(smB + h * 4096 +
                                                 (wc * 64 + j * 16 + l16) * 32 + quad * 8);
#pragma unroll
      for (int i = 0; i < 2; ++i)
#pragma unroll
        for (int j = 0; j < 4; ++j)
          acc[i][j] = __builtin_amdgcn_mfma_f32_16x16x32_bf16(aF[i], bF[j], acc[i][j], 0, 0, 0);
    }
    __syncthreads();
  }
}

__global__ __launch_bounds__(256, 2) void mega(
    const float* __restrict__ hs, const float* __restrict__ wq, const float* __restrict__ wk,
    const float* __restrict__ wv, const float* __restrict__ wo, const float* __restrict__ gate,
    const float* __restrict__ mem, const float* __restrict__ mnorm, float* __restrict__ out,
    float* __restrict__ ksc, float* __restrict__ den, float* __restrict__ qn,
    float* __restrict__ kn, __bf16* __restrict__ kvcT, __bf16* __restrict__ hsb,
    __bf16* __restrict__ wqkvb, __bf16* __restrict__ wob, __bf16* __restrict__ memT,
    __bf16* __restrict__ sqb, __bf16* __restrict__ skb, __bf16* __restrict__ skT,
    __bf16* __restrict__ vT, __bf16* __restrict__ scb, __bf16* __restrict__ kvpT,
    __bf16* __restrict__ combb, __bf16* __restrict__ dvT, unsigned* bar) {
  __shared__ __bf16 smem[20480];  // 40 KB pool, carved per phase
  __shared__ float warr[4];
  int bid = blockIdx.x;
  int tid = threadIdx.x;
  int lane = tid & 63, wave = tid >> 6;
  int wr = wave >> 1, wc = wave & 1, quad = lane >> 4, l16 = lane & 15;

  // ---------------- P0: hs cast (bid<256) + wqkv cast (256..303) ----------------
  if (bid < 256) {
#pragma unroll
    for (int it = 0; it < 16; ++it) {
      int i = bid * 4096 + it * 256 + tid;
      float4 f = reinterpret_cast<const float4*>(hs)[i];
      bf16x4 h = {(__bf16)f.x, (__bf16)f.y, (__bf16)f.z, (__bf16)f.w};
      reinterpret_cast<bf16x4*>(hsb)[i] = h;
    }
  } else if (bid < 304) {
    int t = bid - 256;  // 0..47
    int mat = t >> 4;   // 0..2
    const float* src = (mat == 0) ? wq : (mat == 1) ? wk : wv;
    __bf16* dst = wqkvb + (size_t)mat * (DMEM * HIDDEN);
#pragma unroll
    for (int it = 0; it < 16; ++it) {
      int i = (t & 15) * 4096 + it * 256 + tid;
      float4 f = reinterpret_cast<const float4*>(src)[i];
      bf16x4 h = {(__bf16)f.x, (__bf16)f.y, (__bf16)f.z, (__bf16)f.w};
      reinterpret_cast<bf16x4*>(dst)[i] = h;
    }
  }
  gridbar(bar, 0);

  // P1: QKV GEMM (bid<384) + wo cast (384..399) + memT (400..415) + full seed (416..431)
  if (bid < 384) {
    int m0 = (bid & 63) * 64;
    int by = bid >> 6;  // 0..5
    int wsel = by >> 1, n0 = (by & 1) * 128;
    const __bf16* aptr = hsb + (size_t)(m0 + (tid >> 2)) * HIDDEN + ((tid & 3) << 3);
    const __bf16* bptr = wqkvb + (size_t)(by * 128 + (tid >> 2)) * HIDDEN + ((tid & 3) << 3);
    f32x4 acc[2][4] = {};
    gemm64_bk64(aptr, bptr, HIDDEN, HIDDEN, smem, smem + 8192, wave, wr, wc, quad, l16, acc);
#pragma unroll
    for (int i = 0; i < 2; ++i)
#pragma unroll
      for (int j = 0; j < 4; ++j) {
        int mb = m0 + wr * 32 + i * 16 + quad * 4;
        int n = n0 + wc * 64 + j * 16 + l16;
        if (wsel == 0) {
#pragma unroll
          for (int r = 0; r < 4; ++r)
            sqb[(size_t)(mb + r) * DMEM + n] = (__bf16)elu1(acc[i][j][r]);
        } else if (wsel == 1) {
          bf16x4 t;
#pragma unroll
          for (int r = 0; r < 4; ++r) {
            float v = elu1(acc[i][j][r]);
            skb[(size_t)(mb + r) * DMEM + n] = (__bf16)v;
            t[r] = (__bf16)v;
          }
          *reinterpret_cast<bf16x4*>(skT + (size_t)n * MTOT + mb) = t;
        } else {
          bf16x4 t;
#pragma unroll
          for (int r = 0; r < 4; ++r) t[r] = (__bf16)acc[i][j][r];
          *reinterpret_cast<bf16x4*>(vT + (size_t)n * MTOT + mb) = t;
        }
      }
  } else if (bid < 400) {
    int t = bid - 384;
#pragma unroll
    for (int it = 0; it < 16; ++it) {
      int i = t * 4096 + it * 256 + tid;
      float4 f = reinterpret_cast<const float4*>(wo)[i];
      bf16x4 h = {(__bf16)f.x, (__bf16)f.y, (__bf16)f.z, (__bf16)f.w};
      reinterpret_cast<bf16x4*>(wob)[i] = h;
    }
  } else if (bid < 416) {
    int t = bid - 400;
    int bx = t & 3, by = t >> 2;
    float* sf = reinterpret_cast<float*>(smem);  // [64][65]
    int r0 = tid >> 6, col = tid & 63;
#pragma unroll
    for (int it = 0; it < 16; ++it) {
      int row = it * 4 + r0;
      sf[row * 65 + col] = mem[(size_t)(by * 64 + row) * DMEM + bx * 64 + col];
    }
    __syncthreads();
#pragma unroll
    for (int it = 0; it < 16; ++it) {
      int row = it * 4 + r0;
      memT[(size_t)(bx * 64 + row) * DMEM + by * 64 + col] = (__bf16)sf[col * 65 + row];
    }
  } else if (bid < 432) {  // full new_memory seed: 16 blocks x 4 iters x 256 thr x float4
    int t = bid - 416;
#pragma unroll
    for (int it = 0; it < 4; ++it) {
      int g = t * 1024 + it * 256 + tid;
      reinterpret_cast<float4*>(out + (size_t)MTOT * HIDDEN)[g] =
          reinterpret_cast<const float4*>(mem)[g];
    }
  }
  gridbar(bar, 1);

  // ---- P2: chunk-KV/scores/ksum (bid<352) + qn/kn rows (352..511) ----
  if (bid < 352) {
    int c = bid & 31, y = bid >> 5;  // y in [0,11)
    if (y == 10) {
      int d = tid;
      float s = 0.f;
      for (int i = 0; i < CHUNK; ++i) s += (float)skb[(size_t)(c * CHUNK + i) * DMEM + d];
      ksc[c * DMEM + d] = s;
    } else if (y < 8) {  // kvcT 64x128 tiles
      int e0 = (y >> 1) * 64, d0 = (y & 1) * 128;
      const __bf16* aptr = vT + (size_t)(e0 + (tid >> 2)) * MTOT + c * CHUNK + ((tid & 3) << 3);
      const __bf16* bptr = skT + (size_t)(d0 + (tid >> 2)) * MTOT + c * CHUNK + ((tid & 3) << 3);
      f32x4 acc[2][4] = {};
      gemm64_bk64(aptr, bptr, MTOT, CHUNK, smem, smem + 8192, wave, wr, wc, quad, l16, acc);
#pragma unroll
      for (int i = 0; i < 2; ++i)
#pragma unroll
        for (int j = 0; j < 4; ++j)
#pragma unroll
          for (int r = 0; r < 4; ++r) {
            int e = e0 + wr * 32 + i * 16 + quad * 4 + r;
            int d = d0 + wc * 64 + j * 16 + l16;
            kvcT[(size_t)c * DMEM * DMEM + (size_t)e * DMEM + d] = (__bf16)acc[i][j][r];
          }
    } else {  // causal scores, i0 = (y-8)*64
      int i0 = (y - 8) * 64;
      const __bf16* aptr =
          sqb + (size_t)(c * CHUNK + i0 + (tid >> 2)) * DMEM + ((tid & 3) << 3);
      const __bf16* bptr = skb + (size_t)(c * CHUNK + (tid >> 2)) * DMEM + ((tid & 3) << 3);
      f32x4 acc[2][4] = {};
      gemm64_bk64(aptr, bptr, DMEM, DMEM, smem, smem + 8192, wave, wr, wc, quad, l16, acc);
#pragma unroll
      for (int i = 0; i < 2; ++i)
#pragma unroll
        for (int j = 0; j < 4; ++j)
#pragma unroll
          for (int r = 0; r < 4; ++r) {
            int ii = i0 + wr * 32 + i * 16 + quad * 4 + r;
            int jj = wc * 64 + j * 16 + l16;
            scb[(size_t)c * CHUNK * CHUNK + (size_t)ii * CHUNK + jj] =
                (jj <= ii) ? (__bf16)acc[i][j][r] : (__bf16)0.f;
          }
    }
  } else {  // qn/kn: 640 waves, rows strided
    int wid = (bid - 352) * 4 + wave;  // [0,640)
    for (int m = wid; m < MTOT; m += 640) {
      float s_qn = 0.f, s_kn = 0.f;
      for (int d = lane; d < DMEM; d += 64) {
        float q = (float)sqb[(size_t)m * DMEM + d];
        float k = (float)skb[(size_t)m * DMEM + d];
        float mn = mnorm[d];
        s_qn += q * mn;
        s_kn += k * mn;
      }
#pragma unroll
      for (int off = 32; off > 0; off >>= 1) {
        s_qn += __shfl_down(s_qn, off);
        s_kn += __shfl_down(s_kn, off);
      }
      if (lane == 0) {
        qn[m] = s_qn;
        kn[m] = s_kn;
      }
    }
  }
  gridbar(bar, 2);

  // ---- P3: kvp prefix (bid<128) + den rows (128..383) + dv (384..511) ----
  if (bid < 128) {
    int batch = bid >> 5;
    size_t idx8 = (size_t)(((bid & 31) * 256 + tid)) * 8;
    float run[8] = {};
    for (int c = 0; c < NCH; ++c) {
      size_t off = (size_t)(batch * NCH + c) * DMEM * DMEM + idx8;
      bf16x8 t = *reinterpret_cast<const bf16x8*>(kvcT + off);
      bf16x8 o;
#pragma unroll
      for (int r = 0; r < 8; ++r) o[r] = (__bf16)run[r];
      *reinterpret_cast<bf16x8*>(kvpT + off) = o;
#pragma unroll
      for (int r = 0; r < 8; ++r) run[r] += (float)t[r];
    }
  } else if (bid < 384) {  // den: 1024 waves x 4 rows
    int wid = (bid - 128) * 4 + wave;  // [0,1024)
    for (int m = wid; m < MTOT; m += 1024) {
      int c = m >> 7, i = m & 127, cb = c & ~7;
      float s_sc = 0.f, s_d2 = 0.f;
      for (int j = lane; j < CHUNK; j += 64)
        s_sc += (float)scb[(size_t)c * CHUNK * CHUNK + (size_t)i * CHUNK + j];
      for (int d = lane; d < DMEM; d += 64) {
        float q = (float)sqb[(size_t)m * DMEM + d];
        float kp = 0.f;
        for (int cc = cb; cc < c; ++cc) kp += ksc[cc * DMEM + d];
        s_d2 += q * kp;
      }
#pragma unroll
      for (int off = 32; off > 0; off >>= 1) {
        s_sc += __shfl_down(s_sc, off);
        s_d2 += __shfl_down(s_d2, off);
      }
      if (lane == 0) den[m] = s_sc + s_d2;
    }
  } else {  // dv = v - (sk@memT)/kn -> dvT, 64x128 tiles
    int t = bid - 384;
    int m0 = (t >> 1) * 64, n0 = (t & 1) * 128;
    const __bf16* aptr = skb + (size_t)(m0 + (tid >> 2)) * DMEM + ((tid & 3) << 3);
    const __bf16* bptr = memT + (size_t)(n0 + (tid >> 2)) * DMEM + ((tid & 3) << 3);
    f32x4 acc[2][4] = {};
    gemm64_bk64(aptr, bptr, DMEM, DMEM, smem, smem + 8192, wave, wr, wc, quad, l16, acc);
#pragma unroll
    for (int i = 0; i < 2; ++i) {
      int mb = m0 + wr * 32 + i * 16 + quad * 4;
      float kv[4];
#pragma unroll
      for (int r = 0; r < 4; ++r) kv[r] = fmaxf(kn[mb + r], EPSF);
#pragma unroll
      for (int j = 0; j < 4; ++j) {
        int n = n0 + wc * 64 + j * 16 + l16;
        bf16x4 vv = *reinterpret_cast<const bf16x4*>(vT + (size_t)n * MTOT + mb);
        bf16x4 tt;
#pragma unroll
        for (int r = 0; r < 4; ++r) tt[r] = (__bf16)((float)vv[r] - acc[i][j][r] / kv[r]);
        *reinterpret_cast<bf16x4*>(dvT + (size_t)n * MTOT + mb) = tt;
      }
    }
  }
  gridbar(bar, 3);

  // ---- P4: combine only (bid<128) ----
  if (bid < 128) {
    float mv = mnorm[tid];
#pragma unroll
    for (int off = 32; off > 0; off >>= 1) mv += __shfl_down(mv, off);
    if (lane == 0) warr[wave] = mv;
    __syncthreads();
    float fl = ((warr[0] + warr[1] + warr[2] + warr[3]) < EPSF) ? 0.f : 1.f;
    __syncthreads();
    int c = bid >> 2, yy = bid & 3;
    int i0 = (yy >> 1) * 64, e0 = (yy & 1) * 128;
    f32x4 acc_loc[2][4] = {};
    f32x4 acc_mem[2][4] = {};
    {  // phase 1: scores @ v (K=128)
      const __bf16* aptr =
          scb + (size_t)c * CHUNK * CHUNK + (size_t)(i0 + (tid >> 2)) * CHUNK + ((tid & 3) << 3);
      const __bf16* bptr = vT + (size_t)(e0 + (tid >> 2)) * MTOT + c * CHUNK + ((tid & 3) << 3);
      gemm64_bk64(aptr, bptr, MTOT, CHUNK, smem, smem + 4096, wave, wr, wc, quad, l16, acc_loc);
    }
    {  // phase 2: sq @ kvp + sq @ memT (K=256, dual B)
      const __bf16* aptr = sqb + (size_t)(c * CHUNK + i0 + (tid >> 2)) * DMEM + ((tid & 3) << 3);
      const __bf16* b1ptr =
          kvpT + (size_t)c * DMEM * DMEM + (size_t)(e0 + (tid >> 2)) * DMEM + ((tid & 3) << 3);
      const __bf16* b2ptr = memT + (size_t)(e0 + (tid >> 2)) * DMEM + ((tid & 3) << 3);
      __bf16* As = smem;
      __bf16* B1s = smem + 4096;
      __bf16* B2s = smem + 12288;
      for (int k0 = 0; k0 < DMEM; k0 += 64) {
        stage64(aptr, k0, As, wave);
        stage128(b1ptr, DMEM, k0, B1s, wave);
        stage128(b2ptr, DMEM, k0, B2s, wave);
        __syncthreads();
#pragma unroll
        for (int h = 0; h < 2; ++h) {
          bf16x8 aF[2], b1F[4], b2F[4];
#pragma unroll
          for (int i = 0; i < 2; ++i)
            aF[i] = *reinterpret_cast<const bf16x8*>(As + h * 2048 +
                                                     (wr * 32 + i * 16 + l16) * 32 + quad * 8);
#pragma unroll
          for (int j = 0; j < 4; ++j) {
            b1F[j] = *reinterpret_cast<const bf16x8*>(B1s + h * 4096 +
                                                      (wc * 64 + j * 16 + l16) * 32 + quad * 8);
            b2F[j] = *reinterpret_cast<const bf16x8*>(B2s + h * 4096 +
                                                      (wc * 64 + j * 16 + l16) * 32 + quad * 8);
          }
#pragma unroll
          for (int i = 0; i < 2; ++i)
#pragma unroll
            for (int j = 0; j < 4; ++j) {
              acc_loc[i][j] =
                  __builtin_amdgcn_mfma_f32_16x16x32_bf16(aF[i], b1F[j], acc_loc[i][j], 0, 0, 0);
              acc_mem[i][j] =
                  __builtin_amdgcn_mfma_f32_16x16x32_bf16(aF[i], b2F[j], acc_mem[i][j], 0, 0, 0);
            }
        }
        __syncthreads();
      }
    }
    float g = 1.f / (1.f + __expf(-gate[0]));
#pragma unroll
    for (int i = 0; i < 2; ++i) {
      int mb = c * CHUNK + i0 + wr * 32 + i * 16 + quad * 4;
      float dn[4], qv[4];
#pragma unroll
      for (int r = 0; r < 4; ++r) {
        dn[r] = fmaxf(den[mb + r], EPSF);
        qv[r] = fmaxf(qn[mb + r], EPSF);
      }
#pragma unroll
      for (int j = 0; j < 4; ++j) {
        int e = e0 + wc * 64 + j * 16 + l16;
#pragma unroll
        for (int r = 0; r < 4; ++r) {
          float comb = g * fl * acc_mem[i][j][r] / qv[r] + (1.f - g) * acc_loc[i][j][r] / dn[r];
          combb[(size_t)(mb + r) * DMEM + e] = (__bf16)comb;
        }
      }
    }
  }
}

// -- kF: EXACT R11 code. out-proj (bid<256) + mem-update split-K atomics (256..383)
//    + norm from ksc (384). grid 385 --
__global__ __launch_bounds__(256) void kF(const __bf16* __restrict__ combb,
                                          const __bf16* __restrict__ wob,
                                          const __bf16* __restrict__ skT,
                                          const __bf16* __restrict__ dvT,
                                          const float* __restrict__ ksc,
                                          const float* __restrict__ mnorm,
                                          float* __restrict__ out) {
  __shared__ __bf16 As[8192];
  __shared__ __bf16 Bs[8192];
  int tid = threadIdx.x;
  int bid = blockIdx.x;
  if (bid == 384) {  // new_memory_norm
    int d = tid;
    float s = 0.f;
    for (int c = 0; c < NCHT; ++c) s += ksc[c * DMEM + d];
    out[(size_t)MTOT * HIDDEN + DMEM * DMEM + d] = mnorm[d] + s * (1.f / (float)BATCH);
    return;
  }
  int lane = tid & 63, wave = tid >> 6;
  int wr = wave >> 1, wc = wave & 1, quad = lane >> 4, l16 = lane & 15;
  if (bid < 256) {  // output projection, 128x128 BK=64
    int m0 = (bid & 31) * 128, by = bid >> 5;
    const __bf16* aptr = combb + (size_t)(m0 + (tid >> 2)) * DMEM + ((tid & 3) << 3);
    const __bf16* bptr = wob + (size_t)(by * 128 + (tid >> 2)) * DMEM + ((tid & 3) << 3);
    f32x4 acc[4][4] = {};
    gemm128_bk64(aptr, DMEM, bptr, DMEM, DMEM, As, Bs, wave, wr, wc, quad, l16, acc);
#pragma unroll
    for (int i = 0; i < 4; ++i)
#pragma unroll
      for (int j = 0; j < 4; ++j)
#pragma unroll
        for (int r = 0; r < 4; ++r) {
          int m = m0 + wr * 64 + i * 16 + quad * 4 + r;
          int n = by * 128 + wc * 64 + j * 16 + l16;
          out[(size_t)m * HIDDEN + n] = acc[i][j][r];
        }
  } else {  // mem-update: 16-way split-K (K=256 each), 64x128 tiles, atomics
    int t = bid - 256;
    int kbase = (t >> 3) * 256;
    int yy = t & 7;
    int d0 = (yy >> 1) * 64, e0 = (yy & 1) * 128;
    const __bf16* aptr = skT + (size_t)(d0 + (tid >> 2)) * MTOT + kbase + ((tid & 3) << 3);
    const __bf16* bptr = dvT + (size_t)(e0 + (tid >> 2)) * MTOT + kbase + ((tid & 3) << 3);
    f32x4 acc[2][4] = {};
    gemm64_bk64(aptr, bptr, MTOT, 256, As, Bs, wave, wr, wc, quad, l16, acc);
    float* base = out + (size_t)MTOT * HIDDEN;
#pragma unroll
    for (int i = 0; i < 2; ++i)
#pragma unroll
      for (int j = 0; j < 4; ++j)
#pragma unroll
        for (int r = 0; r < 4; ++r) {
          int d = d0 + wr * 32 + i * 16 + quad * 4 + r;
          int e = e0 + wc * 64 + j * 16 + l16;
          atomicAdd(&base[(size_t)d * DMEM + e], acc[i][j][r] * (1.f / (float)MTOT));
        }
  }
}

extern "C" void kernel_launch(void* const* d_in, const int* in_sizes, int n_in,
                              void* d_out, int out_size, void* d_ws, size_t ws_size,
                              hipStream_t stream) {
  const float* hs = (const float*)d_in[0];
  const float* wq = (const float*)d_in[1];
  const float* wk = (const float*)d_in[2];
  const float* wv = (const float*)d_in[3];
  const float* wo = (const float*)d_in[4];
  const float* gate = (const float*)d_in[5];
  const float* mem = (const float*)d_in[6];
  const float* mnorm = (const float*)d_in[7];
  float* out = (float*)d_out;
  float* ws = (float*)d_ws;

  // fp32 region
  float* ksc = ws;          // 8192
  float* den = ksc + 8192;  // 4096
  float* qn = den + 4096;   // 4096
  float* kn = qn + 4096;    // 4096 (end 20480 floats)
  // bf16 region
  __bf16* kvcT = (__bf16*)(ws + 20480);               // 2097152
  __bf16* hsb = kvcT + (size_t)NCHT * DMEM * DMEM;    // 4194304
  __bf16* wqkvb = hsb + (size_t)MTOT * HIDDEN;        // 786432
  __bf16* wob = wqkvb + (size_t)3 * DMEM * HIDDEN;    // 262144
  __bf16* memT = wob + (size_t)HIDDEN * DMEM;         // 65536
  __bf16* sqb = memT + (size_t)DMEM * DMEM;           // 1048576
  __bf16* skb = sqb + (size_t)MTOT * DMEM;            // 1048576
  __bf16* skT = skb + (size_t)MTOT * DMEM;            // 1048576
  __bf16* vT = skT + (size_t)MTOT * DMEM;             // 1048576
  __bf16* scb = vT + (size_t)MTOT * DMEM;             // 524288
  __bf16* kvpT = scb + (size_t)NCHT * CHUNK * CHUNK;  // 2097152
  __bf16* combb = kvpT + (size_t)NCHT * DMEM * DMEM;  // 1048576
  __bf16* dvT = combb + (size_t)MTOT * DMEM;          // 1048576
  unsigned* bar = (unsigned*)(dvT + (size_t)MTOT * DMEM);  // 4 barrier counters

  hipMemsetAsync(bar, 0, 4 * sizeof(unsigned), stream);
  mega<<<dim3(512), 256, 0, stream>>>(hs, wq, wk, wv, wo, gate, mem, mnorm, out, ksc, den,
                                      qn, kn, kvcT, hsb, wqkvb, wob, memT, sqb, skb, skT,
                                      vT, scb, kvpT, combb, dvT, bar);
  kF<<<dim3(385), 256, 0, stream>>>(combb, wob, skT, dvT, ksc, mnorm, out);
}

// Round 7
// 238.608 us; speedup vs baseline: 2.7474x; 1.6902x over previous
//
#include <hip/hip_runtime.h>

// InfiniAttention — Round 17: back to multi-kernel (R11 structure, 139us proven); the
// software grid barrier costs ~60us each (XCD L2 wb/inv storm) and can never beat ~4us
// kernel boundaries. Changes vs R11: kD ELIMINATED (kvp prefix -> j-loop of K=256 GEMMs
// inside combine; kn inline in dv blocks; den/qn inline in combine blocks); dv moved to
// kC; mem-update+norm moved to kE; out-proj alone in kF. 5 kernels / 4 boundaries.
// Full new_memory seed (R11 covered 1/4). All GEMM bodies byte-identical to R11.

#define HIDDEN 1024
#define DMEM 256
#define BATCH 4
#define SEQ 1024
#define MTOT (BATCH * SEQ)      // 4096
#define CHUNK 128
#define NCH (SEQ / CHUNK)       // 8
#define NCHT (BATCH * NCH)      // 32
#define EPSF 1e-6f

typedef __bf16 bf16x8 __attribute__((ext_vector_type(8)));
typedef __bf16 bf16x4 __attribute__((ext_vector_type(4)));
typedef float f32x4 __attribute__((ext_vector_type(4)));

#define GL_LDS(g, l)                                                                   \
  __builtin_amdgcn_global_load_lds((const __attribute__((address_space(1))) void*)(g), \
                                   (__attribute__((address_space(3))) void*)(l), 16, 0, 0)

__device__ __forceinline__ float elu1(float x) { return x > 0.f ? x + 1.f : __expf(x); }

// Stage a 128-row x 64-col tile as two 32-col slabs (slab h at sm + h*4096).
__device__ __forceinline__ void stage128(const __bf16* p, long ld, int k0, __bf16* sm,
                                         int wave) {
  GL_LDS(p + k0, sm + wave * 512);
  GL_LDS(p + (size_t)64 * ld + k0, sm + 2048 + wave * 512);
  GL_LDS(p + k0 + 32, sm + 4096 + wave * 512);
  GL_LDS(p + (size_t)64 * ld + k0 + 32, sm + 4096 + 2048 + wave * 512);
}
// Stage a 64-row x 64-col tile as two slabs (slab h at sm + h*2048).
__device__ __forceinline__ void stage64(const __bf16* p, int k0, __bf16* sm, int wave) {
  GL_LDS(p + k0, sm + wave * 512);
  GL_LDS(p + k0 + 32, sm + 2048 + wave * 512);
}

// 128x128 tile, BK=64.
__device__ __forceinline__ void gemm128_bk64(const __bf16* aptr, long lda, const __bf16* bptr,
                                             long ldb, int klen, __bf16* smA, __bf16* smB,
                                             int wave, int wr, int wc, int quad, int l16,
                                             f32x4 (&acc)[4][4]) {
  for (int k0 = 0; k0 < klen; k0 += 64) {
    stage128(aptr, lda, k0, smA, wave);
    stage128(bptr, ldb, k0, smB, wave);
    __syncthreads();
#pragma unroll
    for (int h = 0; h < 2; ++h) {
      bf16x8 aF[4], bF[4];
#pragma unroll
      for (int i = 0; i < 4; ++i)
        aF[i] = *reinterpret_cast<const bf16x8*>(smA + h * 4096 +
                                                 (wr * 64 + i * 16 + l16) * 32 + quad * 8);
#pragma unroll
      for (int j = 0; j < 4; ++j)
        bF[j] = *reinterpret_cast<const bf16x8*>(smB + h * 4096 +
                                                 (wc * 64 + j * 16 + l16) * 32 + quad * 8);
#pragma unroll
      for (int i = 0; i < 4; ++i)
#pragma unroll
        for (int j = 0; j < 4; ++j)
          acc[i][j] = __builtin_amdgcn_mfma_f32_16x16x32_bf16(aF[i], bF[j], acc[i][j], 0, 0, 0);
    }
    __syncthreads();
  }
}

// 64x128 tile, BK=64. Accumulates into acc (never zeroes) — used for j-loop prefix.
__device__ __forceinline__ void gemm64_bk64(const __bf16* aptr, const __bf16* bptr, long ldb,
                                            int klen, __bf16* smA, __bf16* smB, int wave,
                                            int wr, int wc, int quad, int l16,
                                            f32x4 (&acc)[2][4]) {
  for (int k0 = 0; k0 < klen; k0 += 64) {
    stage64(aptr, k0, smA, wave);
    stage128(bptr, ldb, k0, smB, wave);
    __syncthreads();
#pragma unroll
    for (int h = 0; h < 2; ++h) {
      bf16x8 aF[2], bF[4];
#pragma unroll
      for (int i = 0; i < 2; ++i)
        aF[i] = *reinterpret_cast<const bf16x8*>(smA + h * 2048 +
                                                 (wr * 32 + i * 16 + l16) * 32 + quad * 8);
#pragma unroll
      for (int j = 0; j < 4; ++j)
        bF[j] = *reinterpret_cast<const bf16x8*>(smB + h * 4096 +
                                                 (wc * 64 + j * 16 + l16) * 32 + quad * 8);
#pragma unroll
      for (int i = 0; i < 2; ++i)
#pragma unroll
        for (int j = 0; j < 4; ++j)
          acc[i][j] = __builtin_amdgcn_mfma_f32_16x16x32_bf16(aF[i], bF[j], acc[i][j], 0, 0, 0);
    }
    __syncthreads();
  }
}

// ---------------- kprep: casts + memT + FULL new_memory seed. grid 5200 ----------------
__global__ void kprep(const float* __restrict__ hs, const float* __restrict__ wq,
                      const float* __restrict__ wk, const float* __restrict__ wv,
                      const float* __restrict__ wo, const float* __restrict__ mem,
                      __bf16* __restrict__ hsb, __bf16* __restrict__ wqkvb,
                      __bf16* __restrict__ wob, __bf16* __restrict__ memT,
                      float* __restrict__ out) {
  __shared__ float s[64][65];
  int b = blockIdx.x, tid = threadIdx.x;
  if (b < 4096) {
    int i = b * 256 + tid;
    float4 f = reinterpret_cast<const float4*>(hs)[i];
    bf16x4 h = {(__bf16)f.x, (__bf16)f.y, (__bf16)f.z, (__bf16)f.w};
    reinterpret_cast<bf16x4*>(hsb)[i] = h;
  } else if (b < 5120) {
    int y = (b - 4096) >> 8;
    const float* src = (y == 0) ? wq : (y == 1) ? wk : (y == 2) ? wv : wo;
    __bf16* dst = (y < 3) ? wqkvb + (size_t)y * (DMEM * HIDDEN) : wob;
    int i = ((b - 4096) & 255) * 256 + tid;
    float4 f = reinterpret_cast<const float4*>(src)[i];
    bf16x4 h = {(__bf16)f.x, (__bf16)f.y, (__bf16)f.z, (__bf16)f.w};
    reinterpret_cast<bf16x4*>(dst)[i] = h;
  } else if (b < 5136) {
    int t = b - 5120;
    int bx = t & 3, by = t >> 2;
    int r0 = tid >> 6, col = tid & 63;
#pragma unroll
    for (int it = 0; it < 16; ++it) {
      int row = it * 4 + r0;
      s[row][col] = mem[(size_t)(by * 64 + row) * DMEM + bx * 64 + col];
    }
    __syncthreads();
#pragma unroll
    for (int it = 0; it < 16; ++it) {
      int row = it * 4 + r0;
      memT[(size_t)(bx * 64 + row) * DMEM + by * 64 + col] = (__bf16)s[col][row];
    }
  } else {  // FULL seed: 64 blocks x 256 thr x float4 = 65536 floats
    int g = (b - 5136) * 256 + tid;
    reinterpret_cast<float4*>(out + (size_t)MTOT * HIDDEN)[g] =
        reinterpret_cast<const float4*>(mem)[g];
  }
}

// ---------------- K1: fused QKV projection, 64x128 BK=64, grid (64,6) ----------------
__global__ __launch_bounds__(256) void k1_qkv_mfma(
    const __bf16* __restrict__ X, const __bf16* __restrict__ W, __bf16* __restrict__ sqb,
    __bf16* __restrict__ skb, __bf16* __restrict__ skT, __bf16* __restrict__ vT) {
  __shared__ __bf16 As[4096];
  __shared__ __bf16 Bs[8192];
  int tid = threadIdx.x;
  int lane = tid & 63, wave = tid >> 6;
  int m0 = blockIdx.x * 64;
  int by = blockIdx.y;
  int wsel = by >> 1, n0 = (by & 1) * 128;
  const __bf16* aptr = X + (size_t)(m0 + (tid >> 2)) * HIDDEN + ((tid & 3) << 3);
  const __bf16* bptr = W + (size_t)(by * 128 + (tid >> 2)) * HIDDEN + ((tid & 3) << 3);
  int wr = wave >> 1, wc = wave & 1, quad = lane >> 4, l16 = lane & 15;
  f32x4 acc[2][4] = {};
  gemm64_bk64(aptr, bptr, HIDDEN, HIDDEN, As, Bs, wave, wr, wc, quad, l16, acc);
#pragma unroll
  for (int i = 0; i < 2; ++i)
#pragma unroll
    for (int j = 0; j < 4; ++j) {
      int mb = m0 + wr * 32 + i * 16 + quad * 4;
      int n = n0 + wc * 64 + j * 16 + l16;
      if (wsel == 0) {
#pragma unroll
        for (int r = 0; r < 4; ++r) sqb[(size_t)(mb + r) * DMEM + n] = (__bf16)elu1(acc[i][j][r]);
      } else if (wsel == 1) {
        bf16x4 t;
#pragma unroll
        for (int r = 0; r < 4; ++r) {
          float v = elu1(acc[i][j][r]);
          skb[(size_t)(mb + r) * DMEM + n] = (__bf16)v;
          t[r] = (__bf16)v;
        }
        *reinterpret_cast<bf16x4*>(skT + (size_t)n * MTOT + mb) = t;
      } else {
        bf16x4 t;
#pragma unroll
        for (int r = 0; r < 4; ++r) t[r] = (__bf16)acc[i][j][r];
        *reinterpret_cast<bf16x4*>(vT + (size_t)n * MTOT + mb) = t;
      }
    }
}

// -- kC2: kvc (y<8) + scores (y=8,9) + ksum (y=10) + dv w/ inline kn (y=11..14).
//    grid (32,15) --
__global__ __launch_bounds__(256) void kC2(const __bf16* __restrict__ vT,
                                           const __bf16* __restrict__ skT,
                                           const __bf16* __restrict__ sqb,
                                           const __bf16* __restrict__ skb,
                                           const __bf16* __restrict__ memT,
                                           const float* __restrict__ mnorm,
                                           __bf16* __restrict__ kvcT, __bf16* __restrict__ scb,
                                           float* __restrict__ ksc, __bf16* __restrict__ dvT) {
  __shared__ __bf16 As[4096];
  __shared__ __bf16 Bs[8192];
  __shared__ float knl[64];
  int tid = threadIdx.x;
  int c = blockIdx.x;
  int y = blockIdx.y;
  if (y == 10) {
    int d = tid;
    float s = 0.f;
    for (int i = 0; i < CHUNK; ++i) s += (float)skb[(size_t)(c * CHUNK + i) * DMEM + d];
    ksc[c * DMEM + d] = s;
    return;
  }
  int lane = tid & 63, wave = tid >> 6;
  int wr = wave >> 1, wc = wave & 1, quad = lane >> 4, l16 = lane & 15;
  if (y < 8) {  // kvcT 64x128 tiles
    int e0 = (y >> 1) * 64, d0 = (y & 1) * 128;
    const __bf16* aptr = vT + (size_t)(e0 + (tid >> 2)) * MTOT + c * CHUNK + ((tid & 3) << 3);
    const __bf16* bptr = skT + (size_t)(d0 + (tid >> 2)) * MTOT + c * CHUNK + ((tid & 3) << 3);
    f32x4 acc[2][4] = {};
    gemm64_bk64(aptr, bptr, MTOT, CHUNK, As, Bs, wave, wr, wc, quad, l16, acc);
#pragma unroll
    for (int i = 0; i < 2; ++i)
#pragma unroll
      for (int j = 0; j < 4; ++j)
#pragma unroll
        for (int r = 0; r < 4; ++r) {
          int e = e0 + wr * 32 + i * 16 + quad * 4 + r;
          int d = d0 + wc * 64 + j * 16 + l16;
          kvcT[(size_t)c * DMEM * DMEM + (size_t)e * DMEM + d] = (__bf16)acc[i][j][r];
        }
  } else if (y < 10) {  // causal scores, i0 = (y-8)*64
    int i0 = (y - 8) * 64;
    const __bf16* aptr = sqb + (size_t)(c * CHUNK + i0 + (tid >> 2)) * DMEM + ((tid & 3) << 3);
    const __bf16* bptr = skb + (size_t)(c * CHUNK + (tid >> 2)) * DMEM + ((tid & 3) << 3);
    f32x4 acc[2][4] = {};
    gemm64_bk64(aptr, bptr, DMEM, DMEM, As, Bs, wave, wr, wc, quad, l16, acc);
#pragma unroll
    for (int i = 0; i < 2; ++i)
#pragma unroll
      for (int j = 0; j < 4; ++j)
#pragma unroll
        for (int r = 0; r < 4; ++r) {
          int ii = i0 + wr * 32 + i * 16 + quad * 4 + r;
          int jj = wc * 64 + j * 16 + l16;
          scb[(size_t)c * CHUNK * CHUNK + (size_t)ii * CHUNK + jj] =
              (jj <= ii) ? (__bf16)acc[i][j][r] : (__bf16)0.f;
        }
  } else {  // dv = v - (sk@memT)/kn -> dvT; kn computed inline. t in [0,128)
    int t = (y - 11) * 32 + c;
    int m0 = (t >> 1) * 64, n0 = (t & 1) * 128;
    // inline kn for rows [m0, m0+64)
    for (int rr = 0; rr < 16; ++rr) {
      int m = m0 + wave * 16 + rr;
      float s = 0.f;
      for (int d = lane; d < DMEM; d += 64) s += (float)skb[(size_t)m * DMEM + d] * mnorm[d];
#pragma unroll
      for (int off = 32; off > 0; off >>= 1) s += __shfl_down(s, off);
      if (lane == 0) knl[wave * 16 + rr] = s;
    }
    __syncthreads();
    const __bf16* aptr = skb + (size_t)(m0 + (tid >> 2)) * DMEM + ((tid & 3) << 3);
    const __bf16* bptr = memT + (size_t)(n0 + (tid >> 2)) * DMEM + ((tid & 3) << 3);
    f32x4 acc[2][4] = {};
    gemm64_bk64(aptr, bptr, DMEM, DMEM, As, Bs, wave, wr, wc, quad, l16, acc);
#pragma unroll
    for (int i = 0; i < 2; ++i) {
      int rel = wr * 32 + i * 16 + quad * 4;
      float kv[4];
#pragma unroll
      for (int r = 0; r < 4; ++r) kv[r] = fmaxf(knl[rel + r], EPSF);
#pragma unroll
      for (int j = 0; j < 4; ++j) {
        int n = n0 + wc * 64 + j * 16 + l16;
        bf16x4 vv = *reinterpret_cast<const bf16x4*>(vT + (size_t)n * MTOT + m0 + rel);
        bf16x4 tt;
#pragma unroll
        for (int r = 0; r < 4; ++r) tt[r] = (__bf16)((float)vv[r] - acc[i][j][r] / kv[r]);
        *reinterpret_cast<bf16x4*>(dvT + (size_t)n * MTOT + m0 + rel) = tt;
      }
    }
  }
}

// -- kE2: combine w/ j-loop prefix + inline den/qn (bid<128) + mem-update (128..255)
//    + norm (256). grid 257 --
__global__ __launch_bounds__(256) void kE2(const __bf16* __restrict__ scb,
                                           const __bf16* __restrict__ sqb,
                                           const __bf16* __restrict__ vT,
                                           const __bf16* __restrict__ kvcT,
                                           const __bf16* __restrict__ memT,
                                           const __bf16* __restrict__ skT,
                                           const __bf16* __restrict__ dvT,
                                           const float* __restrict__ ksc,
                                           const float* __restrict__ gate,
                                           const float* __restrict__ mnorm,
                                           __bf16* __restrict__ combb,
                                           float* __restrict__ out) {
  __shared__ __bf16 As[4096];
  __shared__ __bf16 Bs[8192];
  __shared__ float denl[64];
  __shared__ float qnl[64];
  __shared__ float warr[4];
  int tid = threadIdx.x;
  int bid = blockIdx.x;
  int lane = tid & 63, wave = tid >> 6;
  int wr = wave >> 1, wc = wave & 1, quad = lane >> 4, l16 = lane & 15;
  if (bid == 256) {  // new_memory_norm
    int d = tid;
    float s = 0.f;
    for (int c = 0; c < NCHT; ++c) s += ksc[c * DMEM + d];
    out[(size_t)MTOT * HIDDEN + DMEM * DMEM + d] = mnorm[d] + s * (1.f / (float)BATCH);
    return;
  }
  if (bid < 128) {  // combine
    float mv = mnorm[tid];
#pragma unroll
    for (int off = 32; off > 0; off >>= 1) mv += __shfl_down(mv, off);
    if (lane == 0) warr[wave] = mv;
    __syncthreads();
    float fl = ((warr[0] + warr[1] + warr[2] + warr[3]) < EPSF) ? 0.f : 1.f;
    int c = bid >> 2, yy = bid & 3;
    int i0 = (yy >> 1) * 64, e0 = (yy & 1) * 128;
    int cb = c & ~7;
    // inline den/qn for rows [i0, i0+64) of chunk c
    for (int rr = 0; rr < 16; ++rr) {
      int row = wave * 16 + rr;  // [0,64)
      int m = c * CHUNK + i0 + row;
      float s_sc = 0.f, s_d2 = 0.f, s_qn = 0.f;
      for (int j = lane; j < CHUNK; j += 64)
        s_sc += (float)scb[(size_t)c * CHUNK * CHUNK + (size_t)(i0 + row) * CHUNK + j];
      for (int d = lane; d < DMEM; d += 64) {
        float q = (float)sqb[(size_t)m * DMEM + d];
        float kp = 0.f;
        for (int cc = cb; cc < c; ++cc) kp += ksc[cc * DMEM + d];
        s_d2 += q * kp;
        s_qn += q * mnorm[d];
      }
#pragma unroll
      for (int off = 32; off > 0; off >>= 1) {
        s_sc += __shfl_down(s_sc, off);
        s_d2 += __shfl_down(s_d2, off);
        s_qn += __shfl_down(s_qn, off);
      }
      if (lane == 0) {
        denl[row] = s_sc + s_d2;
        qnl[row] = s_qn;
      }
    }
    __syncthreads();
    f32x4 acc_loc[2][4] = {};
    f32x4 acc_mem[2][4] = {};
    {  // scores @ v (K=128)
      const __bf16* aptr =
          scb + (size_t)c * CHUNK * CHUNK + (size_t)(i0 + (tid >> 2)) * CHUNK + ((tid & 3) << 3);
      const __bf16* bptr = vT + (size_t)(e0 + (tid >> 2)) * MTOT + c * CHUNK + ((tid & 3) << 3);
      gemm64_bk64(aptr, bptr, MTOT, CHUNK, As, Bs, wave, wr, wc, quad, l16, acc_loc);
    }
    const __bf16* aq = sqb + (size_t)(c * CHUNK + i0 + (tid >> 2)) * DMEM + ((tid & 3) << 3);
    // prefix chunks: sq @ kvc_j, j in [cb, c) — K=256 each, fp32 accumulation
    for (int j = cb; j < c; ++j) {
      const __bf16* bj =
          kvcT + (size_t)j * DMEM * DMEM + (size_t)(e0 + (tid >> 2)) * DMEM + ((tid & 3) << 3);
      gemm64_bk64(aq, bj, DMEM, DMEM, As, Bs, wave, wr, wc, quad, l16, acc_loc);
    }
    {  // memory path: sq @ memT (K=256)
      const __bf16* bm = memT + (size_t)(e0 + (tid >> 2)) * DMEM + ((tid & 3) << 3);
      gemm64_bk64(aq, bm, DMEM, DMEM, As, Bs, wave, wr, wc, quad, l16, acc_mem);
    }
    float g = 1.f / (1.f + __expf(-gate[0]));
#pragma unroll
    for (int i = 0; i < 2; ++i) {
      int rel = wr * 32 + i * 16 + quad * 4;  // row within [0,64)
      int mb = c * CHUNK + i0 + rel;
      float dn[4], qv[4];
#pragma unroll
      for (int r = 0; r < 4; ++r) {
        dn[r] = fmaxf(denl[rel + r], EPSF);
        qv[r] = fmaxf(qnl[rel + r], EPSF);
      }
#pragma unroll
      for (int j = 0; j < 4; ++j) {
        int e = e0 + wc * 64 + j * 16 + l16;
#pragma unroll
        for (int r = 0; r < 4; ++r) {
          float comb = g * fl * acc_mem[i][j][r] / qv[r] + (1.f - g) * acc_loc[i][j][r] / dn[r];
          combb[(size_t)(mb + r) * DMEM + e] = (__bf16)comb;
        }
      }
    }
  } else {  // mem-update: 16-way split-K (K=256 each), 64x128 tiles, atomics
    int t = bid - 128;
    int kbase = (t >> 3) * 256;
    int yy = t & 7;
    int d0 = (yy >> 1) * 64, e0 = (yy & 1) * 128;
    const __bf16* aptr = skT + (size_t)(d0 + (tid >> 2)) * MTOT + kbase + ((tid & 3) << 3);
    const __bf16* bptr = dvT + (size_t)(e0 + (tid >> 2)) * MTOT + kbase + ((tid & 3) << 3);
    f32x4 acc[2][4] = {};
    gemm64_bk64(aptr, bptr, MTOT, 256, As, Bs, wave, wr, wc, quad, l16, acc);
    float* base = out + (size_t)MTOT * HIDDEN;
#pragma unroll
    for (int i = 0; i < 2; ++i)
#pragma unroll
      for (int j = 0; j < 4; ++j)
#pragma unroll
        for (int r = 0; r < 4; ++r) {
          int d = d0 + wr * 32 + i * 16 + quad * 4 + r;
          int e = e0 + wc * 64 + j * 16 + l16;
          atomicAdd(&base[(size_t)d * DMEM + e], acc[i][j][r] * (1.f / (float)MTOT));
        }
  }
}

// ---------------- kF2: output projection only, 128x128 BK=64, grid 256 ----------------
__global__ __launch_bounds__(256) void kF2(const __bf16* __restrict__ combb,
                                           const __bf16* __restrict__ wob,
                                           float* __restrict__ out) {
  __shared__ __bf16 As[8192];
  __shared__ __bf16 Bs[8192];
  int tid = threadIdx.x;
  int bid = blockIdx.x;
  int lane = tid & 63, wave = tid >> 6;
  int wr = wave >> 1, wc = wave & 1, quad = lane >> 4, l16 = lane & 15;
  int m0 = (bid & 31) * 128, by = bid >> 5;
  const __bf16* aptr = combb + (size_t)(m0 + (tid >> 2)) * DMEM + ((tid & 3) << 3);
  const __bf16* bptr = wob + (size_t)(by * 128 + (tid >> 2)) * DMEM + ((tid & 3) << 3);
  f32x4 acc[4][4] = {};
  gemm128_bk64(aptr, DMEM, bptr, DMEM, DMEM, As, Bs, wave, wr, wc, quad, l16, acc);
#pragma unroll
  for (int i = 0; i < 4; ++i)
#pragma unroll
    for (int j = 0; j < 4; ++j)
#pragma unroll
      for (int r = 0; r < 4; ++r) {
        int m = m0 + wr * 64 + i * 16 + quad * 4 + r;
        int n = by * 128 + wc * 64 + j * 16 + l16;
        out[(size_t)m * HIDDEN + n] = acc[i][j][r];
      }
}

extern "C" void kernel_launch(void* const* d_in, const int* in_sizes, int n_in,
                              void* d_out, int out_size, void* d_ws, size_t ws_size,
                              hipStream_t stream) {
  const float* hs = (const float*)d_in[0];
  const float* wq = (const float*)d_in[1];
  const float* wk = (const float*)d_in[2];
  const float* wv = (const float*)d_in[3];
  const float* wo = (const float*)d_in[4];
  const float* gate = (const float*)d_in[5];
  const float* mem = (const float*)d_in[6];
  const float* mnorm = (const float*)d_in[7];
  float* out = (float*)d_out;
  float* ws = (float*)d_ws;

  // fp32 region
  float* ksc = ws;  // 8192 (den/qn/kn slots retained but unused)
  // bf16 region
  __bf16* kvcT = (__bf16*)(ws + 20480);               // 2097152
  __bf16* hsb = kvcT + (size_t)NCHT * DMEM * DMEM;    // 4194304
  __bf16* wqkvb = hsb + (size_t)MTOT * HIDDEN;        // 786432
  __bf16* wob = wqkvb + (size_t)3 * DMEM * HIDDEN;    // 262144
  __bf16* memT = wob + (size_t)HIDDEN * DMEM;         // 65536
  __bf16* sqb = memT + (size_t)DMEM * DMEM;           // 1048576
  __bf16* skb = sqb + (size_t)MTOT * DMEM;            // 1048576
  __bf16* skT = skb + (size_t)MTOT * DMEM;            // 1048576
  __bf16* vT = skT + (size_t)MTOT * DMEM;             // 1048576
  __bf16* scb = vT + (size_t)MTOT * DMEM;             // 524288
  __bf16* kvpT = scb + (size_t)NCHT * CHUNK * CHUNK;  // (unused, layout kept)
  __bf16* combb = kvpT + (size_t)NCHT * DMEM * DMEM;  // 1048576
  __bf16* dvT = combb + (size_t)MTOT * DMEM;          // 1048576

  kprep<<<dim3(5200), 256, 0, stream>>>(hs, wq, wk, wv, wo, mem, hsb, wqkvb, wob, memT, out);
  k1_qkv_mfma<<<dim3(64, 6), 256, 0, stream>>>(hsb, wqkvb, sqb, skb, skT, vT);
  kC2<<<dim3(NCHT, 15), 256, 0, stream>>>(vT, skT, sqb, skb, memT, mnorm, kvcT, scb, ksc, dvT);
  kE2<<<dim3(257), 256, 0, stream>>>(scb, sqb, vT, kvcT, memT, skT, dvT, ksc, gate, mnorm,
                                     combb, out);
  kF2<<<dim3(256), 256, 0, stream>>>(combb, wob, out);
}

// Round 8
// 169.409 us; speedup vs baseline: 3.8697x; 1.4085x over previous
//
#include <hip/hip_runtime.h>

// InfiniAttention — Round 18: flattened 6-kernel pipeline from verified pieces only.
// R17's kE2 j-loop (105us, 4% occupancy) reverted to R11's kD-prefix + dual-B combine.
// New vs R11: compact grids (kprep 5200->352 blocks via 16-float4/thread R15 code;
// kD 1152->384 via row loops), dv in kC2 w/ inline kn (R17-verified), memupd+norm in
// kE3 (R17-verified placement), out-proj alone in kF3. Full new_memory seed.

#define HIDDEN 1024
#define DMEM 256
#define BATCH 4
#define SEQ 1024
#define MTOT (BATCH * SEQ)      // 4096
#define CHUNK 128
#define NCH (SEQ / CHUNK)       // 8
#define NCHT (BATCH * NCH)      // 32
#define EPSF 1e-6f

typedef __bf16 bf16x8 __attribute__((ext_vector_type(8)));
typedef __bf16 bf16x4 __attribute__((ext_vector_type(4)));
typedef float f32x4 __attribute__((ext_vector_type(4)));

#define GL_LDS(g, l)                                                                   \
  __builtin_amdgcn_global_load_lds((const __attribute__((address_space(1))) void*)(g), \
                                   (__attribute__((address_space(3))) void*)(l), 16, 0, 0)

__device__ __forceinline__ float elu1(float x) { return x > 0.f ? x + 1.f : __expf(x); }

// Stage a 128-row x 64-col tile as two 32-col slabs (slab h at sm + h*4096).
__device__ __forceinline__ void stage128(const __bf16* p, long ld, int k0, __bf16* sm,
                                         int wave) {
  GL_LDS(p + k0, sm + wave * 512);
  GL_LDS(p + (size_t)64 * ld + k0, sm + 2048 + wave * 512);
  GL_LDS(p + k0 + 32, sm + 4096 + wave * 512);
  GL_LDS(p + (size_t)64 * ld + k0 + 32, sm + 4096 + 2048 + wave * 512);
}
// Stage a 64-row x 64-col tile as two slabs (slab h at sm + h*2048).
__device__ __forceinline__ void stage64(const __bf16* p, int k0, __bf16* sm, int wave) {
  GL_LDS(p + k0, sm + wave * 512);
  GL_LDS(p + k0 + 32, sm + 2048 + wave * 512);
}

// 128x128 tile, BK=64.
__device__ __forceinline__ void gemm128_bk64(const __bf16* aptr, long lda, const __bf16* bptr,
                                             long ldb, int klen, __bf16* smA, __bf16* smB,
                                             int wave, int wr, int wc, int quad, int l16,
                                             f32x4 (&acc)[4][4]) {
  for (int k0 = 0; k0 < klen; k0 += 64) {
    stage128(aptr, lda, k0, smA, wave);
    stage128(bptr, ldb, k0, smB, wave);
    __syncthreads();
#pragma unroll
    for (int h = 0; h < 2; ++h) {
      bf16x8 aF[4], bF[4];
#pragma unroll
      for (int i = 0; i < 4; ++i)
        aF[i] = *reinterpret_cast<const bf16x8*>(smA + h * 4096 +
                                                 (wr * 64 + i * 16 + l16) * 32 + quad * 8);
#pragma unroll
      for (int j = 0; j < 4; ++j)
        bF[j] = *reinterpret_cast<const bf16x8*>(smB + h * 4096 +
                                                 (wc * 64 + j * 16 + l16) * 32 + quad * 8);
#pragma unroll
      for (int i = 0; i < 4; ++i)
#pragma unroll
        for (int j = 0; j < 4; ++j)
          acc[i][j] = __builtin_amdgcn_mfma_f32_16x16x32_bf16(aF[i], bF[j], acc[i][j], 0, 0, 0);
    }
    __syncthreads();
  }
}

// 64x128 tile, BK=64. Accumulates into acc.
__device__ __forceinline__ void gemm64_bk64(const __bf16* aptr, const __bf16* bptr, long ldb,
                                            int klen, __bf16* smA, __bf16* smB, int wave,
                                            int wr, int wc, int quad, int l16,
                                            f32x4 (&acc)[2][4]) {
  for (int k0 = 0; k0 < klen; k0 += 64) {
    stage64(aptr, k0, smA, wave);
    stage128(bptr, ldb, k0, smB, wave);
    __syncthreads();
#pragma unroll
    for (int h = 0; h < 2; ++h) {
      bf16x8 aF[2], bF[4];
#pragma unroll
      for (int i = 0; i < 2; ++i)
        aF[i] = *reinterpret_cast<const bf16x8*>(smA + h * 2048 +
                                                 (wr * 32 + i * 16 + l16) * 32 + quad * 8);
#pragma unroll
      for (int j = 0; j < 4; ++j)
        bF[j] = *reinterpret_cast<const bf16x8*>(smB + h * 4096 +
                                                 (wc * 64 + j * 16 + l16) * 32 + quad * 8);
#pragma unroll
      for (int i = 0; i < 2; ++i)
#pragma unroll
        for (int j = 0; j < 4; ++j)
          acc[i][j] = __builtin_amdgcn_mfma_f32_16x16x32_bf16(aF[i], bF[j], acc[i][j], 0, 0, 0);
    }
    __syncthreads();
  }
}

// -- kprep2: compact casts (R15-P0/P1 verified code). grid 352 --
// bid<256 hs | 256..303 wqkv | 304..319 wo | 320..335 memT | 336..351 seed
__global__ __launch_bounds__(256) void kprep2(
    const float* __restrict__ hs, const float* __restrict__ wq, const float* __restrict__ wk,
    const float* __restrict__ wv, const float* __restrict__ wo, const float* __restrict__ mem,
    __bf16* __restrict__ hsb, __bf16* __restrict__ wqkvb, __bf16* __restrict__ wob,
    __bf16* __restrict__ memT, float* __restrict__ out) {
  __shared__ float s[64][65];
  int b = blockIdx.x, tid = threadIdx.x;
  if (b < 256) {
#pragma unroll
    for (int it = 0; it < 16; ++it) {
      int i = b * 4096 + it * 256 + tid;
      float4 f = reinterpret_cast<const float4*>(hs)[i];
      bf16x4 h = {(__bf16)f.x, (__bf16)f.y, (__bf16)f.z, (__bf16)f.w};
      reinterpret_cast<bf16x4*>(hsb)[i] = h;
    }
  } else if (b < 304) {
    int t = b - 256;  // 0..47
    int mat = t >> 4;
    const float* src = (mat == 0) ? wq : (mat == 1) ? wk : wv;
    __bf16* dst = wqkvb + (size_t)mat * (DMEM * HIDDEN);
#pragma unroll
    for (int it = 0; it < 16; ++it) {
      int i = (t & 15) * 4096 + it * 256 + tid;
      float4 f = reinterpret_cast<const float4*>(src)[i];
      bf16x4 h = {(__bf16)f.x, (__bf16)f.y, (__bf16)f.z, (__bf16)f.w};
      reinterpret_cast<bf16x4*>(dst)[i] = h;
    }
  } else if (b < 320) {
    int t = b - 304;
#pragma unroll
    for (int it = 0; it < 16; ++it) {
      int i = t * 4096 + it * 256 + tid;
      float4 f = reinterpret_cast<const float4*>(wo)[i];
      bf16x4 h = {(__bf16)f.x, (__bf16)f.y, (__bf16)f.z, (__bf16)f.w};
      reinterpret_cast<bf16x4*>(wob)[i] = h;
    }
  } else if (b < 336) {
    int t = b - 320;
    int bx = t & 3, by = t >> 2;
    int r0 = tid >> 6, col = tid & 63;
#pragma unroll
    for (int it = 0; it < 16; ++it) {
      int row = it * 4 + r0;
      s[row][col] = mem[(size_t)(by * 64 + row) * DMEM + bx * 64 + col];
    }
    __syncthreads();
#pragma unroll
    for (int it = 0; it < 16; ++it) {
      int row = it * 4 + r0;
      memT[(size_t)(bx * 64 + row) * DMEM + by * 64 + col] = (__bf16)s[col][row];
    }
  } else {  // full new_memory seed: 16 blocks x 4 iters
    int t = b - 336;
#pragma unroll
    for (int it = 0; it < 4; ++it) {
      int g = t * 1024 + it * 256 + tid;
      reinterpret_cast<float4*>(out + (size_t)MTOT * HIDDEN)[g] =
          reinterpret_cast<const float4*>(mem)[g];
    }
  }
}

// ---------------- K1: fused QKV projection, 64x128 BK=64, grid (64,6) ----------------
__global__ __launch_bounds__(256) void k1_qkv_mfma(
    const __bf16* __restrict__ X, const __bf16* __restrict__ W, __bf16* __restrict__ sqb,
    __bf16* __restrict__ skb, __bf16* __restrict__ skT, __bf16* __restrict__ vT) {
  __shared__ __bf16 As[4096];
  __shared__ __bf16 Bs[8192];
  int tid = threadIdx.x;
  int lane = tid & 63, wave = tid >> 6;
  int m0 = blockIdx.x * 64;
  int by = blockIdx.y;
  int wsel = by >> 1, n0 = (by & 1) * 128;
  const __bf16* aptr = X + (size_t)(m0 + (tid >> 2)) * HIDDEN + ((tid & 3) << 3);
  const __bf16* bptr = W + (size_t)(by * 128 + (tid >> 2)) * HIDDEN + ((tid & 3) << 3);
  int wr = wave >> 1, wc = wave & 1, quad = lane >> 4, l16 = lane & 15;
  f32x4 acc[2][4] = {};
  gemm64_bk64(aptr, bptr, HIDDEN, HIDDEN, As, Bs, wave, wr, wc, quad, l16, acc);
#pragma unroll
  for (int i = 0; i < 2; ++i)
#pragma unroll
    for (int j = 0; j < 4; ++j) {
      int mb = m0 + wr * 32 + i * 16 + quad * 4;
      int n = n0 + wc * 64 + j * 16 + l16;
      if (wsel == 0) {
#pragma unroll
        for (int r = 0; r < 4; ++r) sqb[(size_t)(mb + r) * DMEM + n] = (__bf16)elu1(acc[i][j][r]);
      } else if (wsel == 1) {
        bf16x4 t;
#pragma unroll
        for (int r = 0; r < 4; ++r) {
          float v = elu1(acc[i][j][r]);
          skb[(size_t)(mb + r) * DMEM + n] = (__bf16)v;
          t[r] = (__bf16)v;
        }
        *reinterpret_cast<bf16x4*>(skT + (size_t)n * MTOT + mb) = t;
      } else {
        bf16x4 t;
#pragma unroll
        for (int r = 0; r < 4; ++r) t[r] = (__bf16)acc[i][j][r];
        *reinterpret_cast<bf16x4*>(vT + (size_t)n * MTOT + mb) = t;
      }
    }
}

// -- kC2 (R17-verified): kvc (y<8) + scores (y=8,9) + ksum (y=10) + dv w/ inline kn
//    (y=11..14). grid (32,15) --
__global__ __launch_bounds__(256) void kC2(const __bf16* __restrict__ vT,
                                           const __bf16* __restrict__ skT,
                                           const __bf16* __restrict__ sqb,
                                           const __bf16* __restrict__ skb,
                                           const __bf16* __restrict__ memT,
                                           const float* __restrict__ mnorm,
                                           __bf16* __restrict__ kvcT, __bf16* __restrict__ scb,
                                           float* __restrict__ ksc, __bf16* __restrict__ dvT) {
  __shared__ __bf16 As[4096];
  __shared__ __bf16 Bs[8192];
  __shared__ float knl[64];
  int tid = threadIdx.x;
  int c = blockIdx.x;
  int y = blockIdx.y;
  if (y == 10) {
    int d = tid;
    float s = 0.f;
    for (int i = 0; i < CHUNK; ++i) s += (float)skb[(size_t)(c * CHUNK + i) * DMEM + d];
    ksc[c * DMEM + d] = s;
    return;
  }
  int lane = tid & 63, wave = tid >> 6;
  int wr = wave >> 1, wc = wave & 1, quad = lane >> 4, l16 = lane & 15;
  if (y < 8) {  // kvcT 64x128 tiles
    int e0 = (y >> 1) * 64, d0 = (y & 1) * 128;
    const __bf16* aptr = vT + (size_t)(e0 + (tid >> 2)) * MTOT + c * CHUNK + ((tid & 3) << 3);
    const __bf16* bptr = skT + (size_t)(d0 + (tid >> 2)) * MTOT + c * CHUNK + ((tid & 3) << 3);
    f32x4 acc[2][4] = {};
    gemm64_bk64(aptr, bptr, MTOT, CHUNK, As, Bs, wave, wr, wc, quad, l16, acc);
#pragma unroll
    for (int i = 0; i < 2; ++i)
#pragma unroll
      for (int j = 0; j < 4; ++j)
#pragma unroll
        for (int r = 0; r < 4; ++r) {
          int e = e0 + wr * 32 + i * 16 + quad * 4 + r;
          int d = d0 + wc * 64 + j * 16 + l16;
          kvcT[(size_t)c * DMEM * DMEM + (size_t)e * DMEM + d] = (__bf16)acc[i][j][r];
        }
  } else if (y < 10) {  // causal scores, i0 = (y-8)*64
    int i0 = (y - 8) * 64;
    const __bf16* aptr = sqb + (size_t)(c * CHUNK + i0 + (tid >> 2)) * DMEM + ((tid & 3) << 3);
    const __bf16* bptr = skb + (size_t)(c * CHUNK + (tid >> 2)) * DMEM + ((tid & 3) << 3);
    f32x4 acc[2][4] = {};
    gemm64_bk64(aptr, bptr, DMEM, DMEM, As, Bs, wave, wr, wc, quad, l16, acc);
#pragma unroll
    for (int i = 0; i < 2; ++i)
#pragma unroll
      for (int j = 0; j < 4; ++j)
#pragma unroll
        for (int r = 0; r < 4; ++r) {
          int ii = i0 + wr * 32 + i * 16 + quad * 4 + r;
          int jj = wc * 64 + j * 16 + l16;
          scb[(size_t)c * CHUNK * CHUNK + (size_t)ii * CHUNK + jj] =
              (jj <= ii) ? (__bf16)acc[i][j][r] : (__bf16)0.f;
        }
  } else {  // dv = v - (sk@memT)/kn -> dvT; kn inline. t in [0,128)
    int t = (y - 11) * 32 + c;
    int m0 = (t >> 1) * 64, n0 = (t & 1) * 128;
    for (int rr = 0; rr < 16; ++rr) {
      int m = m0 + wave * 16 + rr;
      float s = 0.f;
      for (int d = lane; d < DMEM; d += 64) s += (float)skb[(size_t)m * DMEM + d] * mnorm[d];
#pragma unroll
      for (int off = 32; off > 0; off >>= 1) s += __shfl_down(s, off);
      if (lane == 0) knl[wave * 16 + rr] = s;
    }
    __syncthreads();
    const __bf16* aptr = skb + (size_t)(m0 + (tid >> 2)) * DMEM + ((tid & 3) << 3);
    const __bf16* bptr = memT + (size_t)(n0 + (tid >> 2)) * DMEM + ((tid & 3) << 3);
    f32x4 acc[2][4] = {};
    gemm64_bk64(aptr, bptr, DMEM, DMEM, As, Bs, wave, wr, wc, quad, l16, acc);
#pragma unroll
    for (int i = 0; i < 2; ++i) {
      int rel = wr * 32 + i * 16 + quad * 4;
      float kv[4];
#pragma unroll
      for (int r = 0; r < 4; ++r) kv[r] = fmaxf(knl[rel + r], EPSF);
#pragma unroll
      for (int j = 0; j < 4; ++j) {
        int n = n0 + wc * 64 + j * 16 + l16;
        bf16x4 vv = *reinterpret_cast<const bf16x4*>(vT + (size_t)n * MTOT + m0 + rel);
        bf16x4 tt;
#pragma unroll
        for (int r = 0; r < 4; ++r) tt[r] = (__bf16)((float)vv[r] - acc[i][j][r] / kv[r]);
        *reinterpret_cast<bf16x4*>(dvT + (size_t)n * MTOT + m0 + rel) = tt;
      }
    }
  }
}

// -- kD2: prefix (bid<128, R11 code) + den/qn rows looped (128..383). grid 384 --
__global__ __launch_bounds__(256) void kD2(const __bf16* __restrict__ kvcT,
                                           __bf16* __restrict__ kvpT,
                                           const float* __restrict__ ksc,
                                           const __bf16* __restrict__ scb,
                                           const __bf16* __restrict__ sqb,
                                           const float* __restrict__ mnorm,
                                           float* __restrict__ den, float* __restrict__ qn) {
  int bid = blockIdx.x;
  int tid = threadIdx.x;
  if (bid < 128) {
    int batch = bid >> 5;
    size_t idx8 = (size_t)(((bid & 31) * 256 + tid)) * 8;
    float run[8] = {};
    for (int c = 0; c < NCH; ++c) {
      size_t off = (size_t)(batch * NCH + c) * DMEM * DMEM + idx8;
      bf16x8 t = *reinterpret_cast<const bf16x8*>(kvcT + off);
      bf16x8 o;
#pragma unroll
      for (int r = 0; r < 8; ++r) o[r] = (__bf16)run[r];
      *reinterpret_cast<bf16x8*>(kvpT + off) = o;
#pragma unroll
      for (int r = 0; r < 8; ++r) run[r] += (float)t[r];
    }
  } else {  // den/qn: 1024 waves x 4 rows (R15-P3-verified loop pattern)
    int wave = tid >> 6, lane = tid & 63;
    int wid = (bid - 128) * 4 + wave;  // [0,1024)
    for (int m = wid; m < MTOT; m += 1024) {
      int c = m >> 7, i = m & 127, cb = c & ~7;
      float s_sc = 0.f, s_d2 = 0.f, s_qn = 0.f;
      for (int j = lane; j < CHUNK; j += 64)
        s_sc += (float)scb[(size_t)c * CHUNK * CHUNK + (size_t)i * CHUNK + j];
      for (int d = lane; d < DMEM; d += 64) {
        float q = (float)sqb[(size_t)m * DMEM + d];
        float kp = 0.f;
        for (int cc = cb; cc < c; ++cc) kp += ksc[cc * DMEM + d];
        s_d2 += q * kp;
        s_qn += q * mnorm[d];
      }
#pragma unroll
      for (int off = 32; off > 0; off >>= 1) {
        s_sc += __shfl_down(s_sc, off);
        s_d2 += __shfl_down(s_d2, off);
        s_qn += __shfl_down(s_qn, off);
      }
      if (lane == 0) {
        den[m] = s_sc + s_d2;
        qn[m] = s_qn;
      }
    }
  }
}

// -- kE3: combine (bid<128, R11 kE code) + mem-update (128..255, R11 kF code)
//    + norm (256, R11 kF code). grid 257 --
__global__ __launch_bounds__(256) void kE3(const __bf16* __restrict__ scb,
                                           const __bf16* __restrict__ sqb,
                                           const __bf16* __restrict__ vT,
                                           const __bf16* __restrict__ kvpT,
                                           const __bf16* __restrict__ memT,
                                           const __bf16* __restrict__ skT,
                                           const __bf16* __restrict__ dvT,
                                           const float* __restrict__ ksc,
                                           const float* __restrict__ den,
                                           const float* __restrict__ qn,
                                           const float* __restrict__ gate,
                                           const float* __restrict__ mnorm,
                                           __bf16* __restrict__ combb,
                                           float* __restrict__ out) {
  __shared__ __bf16 As[4096];
  __shared__ __bf16 B1s[8192];
  __shared__ __bf16 B2s[8192];
  __shared__ float warr[4];
  int tid = threadIdx.x;
  int bid = blockIdx.x;
  int lane = tid & 63, wave = tid >> 6;
  int wr = wave >> 1, wc = wave & 1, quad = lane >> 4, l16 = lane & 15;
  if (bid == 256) {  // new_memory_norm
    int d = tid;
    float s = 0.f;
    for (int c = 0; c < NCHT; ++c) s += ksc[c * DMEM + d];
    out[(size_t)MTOT * HIDDEN + DMEM * DMEM + d] = mnorm[d] + s * (1.f / (float)BATCH);
    return;
  }
  if (bid < 128) {  // combine (R11 kE verified)
    float mv = mnorm[tid];
#pragma unroll
    for (int off = 32; off > 0; off >>= 1) mv += __shfl_down(mv, off);
    if (lane == 0) warr[wave] = mv;
    __syncthreads();
    float fl = ((warr[0] + warr[1] + warr[2] + warr[3]) < EPSF) ? 0.f : 1.f;
    __syncthreads();
    int c = bid >> 2, yy = bid & 3;
    int i0 = (yy >> 1) * 64, e0 = (yy & 1) * 128;
    f32x4 acc_loc[2][4] = {};
    f32x4 acc_mem[2][4] = {};
    {  // phase 1: scores @ v (K=128)
      const __bf16* aptr =
          scb + (size_t)c * CHUNK * CHUNK + (size_t)(i0 + (tid >> 2)) * CHUNK + ((tid & 3) << 3);
      const __bf16* bptr = vT + (size_t)(e0 + (tid >> 2)) * MTOT + c * CHUNK + ((tid & 3) << 3);
      gemm64_bk64(aptr, bptr, MTOT, CHUNK, As, B1s, wave, wr, wc, quad, l16, acc_loc);
    }
    {  // phase 2: sq @ kvp + sq @ memT (K=256, dual B)
      const __bf16* aptr = sqb + (size_t)(c * CHUNK + i0 + (tid >> 2)) * DMEM + ((tid & 3) << 3);
      const __bf16* b1ptr =
          kvpT + (size_t)c * DMEM * DMEM + (size_t)(e0 + (tid >> 2)) * DMEM + ((tid & 3) << 3);
      const __bf16* b2ptr = memT + (size_t)(e0 + (tid >> 2)) * DMEM + ((tid & 3) << 3);
      for (int k0 = 0; k0 < DMEM; k0 += 64) {
        stage64(aptr, k0, As, wave);
        stage128(b1ptr, DMEM, k0, B1s, wave);
        stage128(b2ptr, DMEM, k0, B2s, wave);
        __syncthreads();
#pragma unroll
        for (int h = 0; h < 2; ++h) {
          bf16x8 aF[2], b1F[4], b2F[4];
#pragma unroll
          for (int i = 0; i < 2; ++i)
            aF[i] = *reinterpret_cast<const bf16x8*>(As + h * 2048 +
                                                     (wr * 32 + i * 16 + l16) * 32 + quad * 8);
#pragma unroll
          for (int j = 0; j < 4; ++j) {
            b1F[j] = *reinterpret_cast<const bf16x8*>(B1s + h * 4096 +
                                                      (wc * 64 + j * 16 + l16) * 32 + quad * 8);
            b2F[j] = *reinterpret_cast<const bf16x8*>(B2s + h * 4096 +
                                                      (wc * 64 + j * 16 + l16) * 32 + quad * 8);
          }
#pragma unroll
          for (int i = 0; i < 2; ++i)
#pragma unroll
            for (int j = 0; j < 4; ++j) {
              acc_loc[i][j] =
                  __builtin_amdgcn_mfma_f32_16x16x32_bf16(aF[i], b1F[j], acc_loc[i][j], 0, 0, 0);
              acc_mem[i][j] =
                  __builtin_amdgcn_mfma_f32_16x16x32_bf16(aF[i], b2F[j], acc_mem[i][j], 0, 0, 0);
            }
        }
        __syncthreads();
      }
    }
    float g = 1.f / (1.f + __expf(-gate[0]));
#pragma unroll
    for (int i = 0; i < 2; ++i) {
      int mb = c * CHUNK + i0 + wr * 32 + i * 16 + quad * 4;
      float dn[4], qv[4];
#pragma unroll
      for (int r = 0; r < 4; ++r) {
        dn[r] = fmaxf(den[mb + r], EPSF);
        qv[r] = fmaxf(qn[mb + r], EPSF);
      }
#pragma unroll
      for (int j = 0; j < 4; ++j) {
        int e = e0 + wc * 64 + j * 16 + l16;
#pragma unroll
        for (int r = 0; r < 4; ++r) {
          float comb = g * fl * acc_mem[i][j][r] / qv[r] + (1.f - g) * acc_loc[i][j][r] / dn[r];
          combb[(size_t)(mb + r) * DMEM + e] = (__bf16)comb;
        }
      }
    }
  } else {  // mem-update: 16-way split-K (K=256 each), 64x128 tiles, atomics (R8-proven)
    int t = bid - 128;
    int kbase = (t >> 3) * 256;
    int yy = t & 7;
    int d0 = (yy >> 1) * 64, e0 = (yy & 1) * 128;
    const __bf16* aptr = skT + (size_t)(d0 + (tid >> 2)) * MTOT + kbase + ((tid & 3) << 3);
    const __bf16* bptr = dvT + (size_t)(e0 + (tid >> 2)) * MTOT + kbase + ((tid & 3) << 3);
    f32x4 acc[2][4] = {};
    gemm64_bk64(aptr, bptr, MTOT, 256, As, B1s, wave, wr, wc, quad, l16, acc);
    float* base = out + (size_t)MTOT * HIDDEN;
#pragma unroll
    for (int i = 0; i < 2; ++i)
#pragma unroll
      for (int j = 0; j < 4; ++j)
#pragma unroll
        for (int r = 0; r < 4; ++r) {
          int d = d0 + wr * 32 + i * 16 + quad * 4 + r;
          int e = e0 + wc * 64 + j * 16 + l16;
          atomicAdd(&base[(size_t)d * DMEM + e], acc[i][j][r] * (1.f / (float)MTOT));
        }
  }
}

// ---------------- kF3: output projection only, 128x128 BK=64, grid 256 ----------------
__global__ __launch_bounds__(256) void kF3(const __bf16* __restrict__ combb,
                                           const __bf16* __restrict__ wob,
                                           float* __restrict__ out) {
  __shared__ __bf16 As[8192];
  __shared__ __bf16 Bs[8192];
  int tid = threadIdx.x;
  int bid = blockIdx.x;
  int lane = tid & 63, wave = tid >> 6;
  int wr = wave >> 1, wc = wave & 1, quad = lane >> 4, l16 = lane & 15;
  int m0 = (bid & 31) * 128, by = bid >> 5;
  const __bf16* aptr = combb + (size_t)(m0 + (tid >> 2)) * DMEM + ((tid & 3) << 3);
  const __bf16* bptr = wob + (size_t)(by * 128 + (tid >> 2)) * DMEM + ((tid & 3) << 3);
  f32x4 acc[4][4] = {};
  gemm128_bk64(aptr, DMEM, bptr, DMEM, DMEM, As, Bs, wave, wr, wc, quad, l16, acc);
#pragma unroll
  for (int i = 0; i < 4; ++i)
#pragma unroll
    for (int j = 0; j < 4; ++j)
#pragma unroll
      for (int r = 0; r < 4; ++r) {
        int m = m0 + wr * 64 + i * 16 + quad * 4 + r;
        int n = by * 128 + wc * 64 + j * 16 + l16;
        out[(size_t)m * HIDDEN + n] = acc[i][j][r];
      }
}

extern "C" void kernel_launch(void* const* d_in, const int* in_sizes, int n_in,
                              void* d_out, int out_size, void* d_ws, size_t ws_size,
                              hipStream_t stream) {
  const float* hs = (const float*)d_in[0];
  const float* wq = (const float*)d_in[1];
  const float* wk = (const float*)d_in[2];
  const float* wv = (const float*)d_in[3];
  const float* wo = (const float*)d_in[4];
  const float* gate = (const float*)d_in[5];
  const float* mem = (const float*)d_in[6];
  const float* mnorm = (const float*)d_in[7];
  float* out = (float*)d_out;
  float* ws = (float*)d_ws;

  // fp32 region
  float* ksc = ws;          // 8192
  float* den = ksc + 8192;  // 4096
  float* qn = den + 4096;   // 4096
  float* kn = qn + 4096;    // 4096 (unused; layout kept)
  (void)kn;
  // bf16 region
  __bf16* kvcT = (__bf16*)(ws + 20480);               // 2097152
  __bf16* hsb = kvcT + (size_t)NCHT * DMEM * DMEM;    // 4194304
  __bf16* wqkvb = hsb + (size_t)MTOT * HIDDEN;        // 786432
  __bf16* wob = wqkvb + (size_t)3 * DMEM * HIDDEN;    // 262144
  __bf16* memT = wob + (size_t)HIDDEN * DMEM;         // 65536
  __bf16* sqb = memT + (size_t)DMEM * DMEM;           // 1048576
  __bf16* skb = sqb + (size_t)MTOT * DMEM;            // 1048576
  __bf16* skT = skb + (size_t)MTOT * DMEM;            // 1048576
  __bf16* vT = skT + (size_t)MTOT * DMEM;             // 1048576
  __bf16* scb = vT + (size_t)MTOT * DMEM;             // 524288
  __bf16* kvpT = scb + (size_t)NCHT * CHUNK * CHUNK;  // 2097152
  __bf16* combb = kvpT + (size_t)NCHT * DMEM * DMEM;  // 1048576
  __bf16* dvT = combb + (size_t)MTOT * DMEM;          // 1048576

  kprep2<<<dim3(352), 256, 0, stream>>>(hs, wq, wk, wv, wo, mem, hsb, wqkvb, wob, memT, out);
  k1_qkv_mfma<<<dim3(64, 6), 256, 0, stream>>>(hsb, wqkvb, sqb, skb, skT, vT);
  kC2<<<dim3(NCHT, 15), 256, 0, stream>>>(vT, skT, sqb, skb, memT, mnorm, kvcT, scb, ksc, dvT);
  kD2<<<dim3(384), 256, 0, stream>>>(kvcT, kvpT, ksc, scb, sqb, mnorm, den, qn);
  kE3<<<dim3(257), 256, 0, stream>>>(scb, sqb, vT, kvpT, memT, skT, dvT, ksc, den, qn, gate,
                                     mnorm, combb, out);
  kF3<<<dim3(256), 256, 0, stream>>>(combb, wob, out);
}

// Round 9
// 135.042 us; speedup vs baseline: 4.8545x; 1.2545x over previous
//
#include <hip/hip_runtime.h>

// InfiniAttention — Round 19: R11 exact structure/code (139.2us proven) + three surgical
// fixes: (1) kD den-loop predicated unroll (runtime-bound cc-loop serialized its loads;
// now 7 independent predicated loads, bitwise-identical sum); (2) kD prefix hoists the
// 8 chunk loads ahead of the running sum; (3) full new_memory seed (R11 covered 1/4;
// absmax 0.423 -> 0.0078, proven R15-R18). Grid balances untouched — R17/R18 showed
// latency-bound row-scalar kernels need max wave count (kD 1152, kprep 5200).

#define HIDDEN 1024
#define DMEM 256
#define BATCH 4
#define SEQ 1024
#define MTOT (BATCH * SEQ)      // 4096
#define CHUNK 128
#define NCH (SEQ / CHUNK)       // 8
#define NCHT (BATCH * NCH)      // 32
#define EPSF 1e-6f

typedef __bf16 bf16x8 __attribute__((ext_vector_type(8)));
typedef __bf16 bf16x4 __attribute__((ext_vector_type(4)));
typedef float f32x4 __attribute__((ext_vector_type(4)));

#define GL_LDS(g, l)                                                                   \
  __builtin_amdgcn_global_load_lds((const __attribute__((address_space(1))) void*)(g), \
                                   (__attribute__((address_space(3))) void*)(l), 16, 0, 0)

__device__ __forceinline__ float elu1(float x) { return x > 0.f ? x + 1.f : __expf(x); }

// Stage a 128-row x 64-col tile as two 32-col slabs (slab h at sm + h*4096).
__device__ __forceinline__ void stage128(const __bf16* p, long ld, int k0, __bf16* sm,
                                         int wave) {
  GL_LDS(p + k0, sm + wave * 512);
  GL_LDS(p + (size_t)64 * ld + k0, sm + 2048 + wave * 512);
  GL_LDS(p + k0 + 32, sm + 4096 + wave * 512);
  GL_LDS(p + (size_t)64 * ld + k0 + 32, sm + 4096 + 2048 + wave * 512);
}
// Stage a 64-row x 64-col tile as two slabs (slab h at sm + h*2048).
__device__ __forceinline__ void stage64(const __bf16* p, int k0, __bf16* sm, int wave) {
  GL_LDS(p + k0, sm + wave * 512);
  GL_LDS(p + k0 + 32, sm + 2048 + wave * 512);
}

// 128x128 tile, BK=64.
__device__ __forceinline__ void gemm128_bk64(const __bf16* aptr, long lda, const __bf16* bptr,
                                             long ldb, int klen, __bf16* smA, __bf16* smB,
                                             int wave, int wr, int wc, int quad, int l16,
                                             f32x4 (&acc)[4][4]) {
  for (int k0 = 0; k0 < klen; k0 += 64) {
    stage128(aptr, lda, k0, smA, wave);
    stage128(bptr, ldb, k0, smB, wave);
    __syncthreads();
#pragma unroll
    for (int h = 0; h < 2; ++h) {
      bf16x8 aF[4], bF[4];
#pragma unroll
      for (int i = 0; i < 4; ++i)
        aF[i] = *reinterpret_cast<const bf16x8*>(smA + h * 4096 +
                                                 (wr * 64 + i * 16 + l16) * 32 + quad * 8);
#pragma unroll
      for (int j = 0; j < 4; ++j)
        bF[j] = *reinterpret_cast<const bf16x8*>(smB + h * 4096 +
                                                 (wc * 64 + j * 16 + l16) * 32 + quad * 8);
#pragma unroll
      for (int i = 0; i < 4; ++i)
#pragma unroll
        for (int j = 0; j < 4; ++j)
          acc[i][j] = __builtin_amdgcn_mfma_f32_16x16x32_bf16(aF[i], bF[j], acc[i][j], 0, 0, 0);
    }
    __syncthreads();
  }
}

// 64x128 tile, BK=64.
__device__ __forceinline__ void gemm64_bk64(const __bf16* aptr, const __bf16* bptr, long ldb,
                                            int klen, __bf16* smA, __bf16* smB, int wave,
                                            int wr, int wc, int quad, int l16,
                                            f32x4 (&acc)[2][4]) {
  for (int k0 = 0; k0 < klen; k0 += 64) {
    stage64(aptr, k0, smA, wave);
    stage128(bptr, ldb, k0, smB, wave);
    __syncthreads();
#pragma unroll
    for (int h = 0; h < 2; ++h) {
      bf16x8 aF[2], bF[4];
#pragma unroll
      for (int i = 0; i < 2; ++i)
        aF[i] = *reinterpret_cast<const bf16x8*>(smA + h * 2048 +
                                                 (wr * 32 + i * 16 + l16) * 32 + quad * 8);
#pragma unroll
      for (int j = 0; j < 4; ++j)
        bF[j] = *reinterpret_cast<const bf16x8*>(smB + h * 4096 +
                                                 (wc * 64 + j * 16 + l16) * 32 + quad * 8);
#pragma unroll
      for (int i = 0; i < 2; ++i)
#pragma unroll
        for (int j = 0; j < 4; ++j)
          acc[i][j] = __builtin_amdgcn_mfma_f32_16x16x32_bf16(aF[i], bF[j], acc[i][j], 0, 0, 0);
    }
    __syncthreads();
  }
}

// ---------------- kprep: casts + memT + FULL new_memory seed. grid 5200 ----------------
__global__ void kprep(const float* __restrict__ hs, const float* __restrict__ wq,
                      const float* __restrict__ wk, const float* __restrict__ wv,
                      const float* __restrict__ wo, const float* __restrict__ mem,
                      __bf16* __restrict__ hsb, __bf16* __restrict__ wqkvb,
                      __bf16* __restrict__ wob, __bf16* __restrict__ memT,
                      float* __restrict__ out) {
  __shared__ float s[64][65];
  int b = blockIdx.x, tid = threadIdx.x;
  if (b < 4096) {
    int i = b * 256 + tid;
    float4 f = reinterpret_cast<const float4*>(hs)[i];
    bf16x4 h = {(__bf16)f.x, (__bf16)f.y, (__bf16)f.z, (__bf16)f.w};
    reinterpret_cast<bf16x4*>(hsb)[i] = h;
  } else if (b < 5120) {
    int y = (b - 4096) >> 8;
    const float* src = (y == 0) ? wq : (y == 1) ? wk : (y == 2) ? wv : wo;
    __bf16* dst = (y < 3) ? wqkvb + (size_t)y * (DMEM * HIDDEN) : wob;
    int i = ((b - 4096) & 255) * 256 + tid;
    float4 f = reinterpret_cast<const float4*>(src)[i];
    bf16x4 h = {(__bf16)f.x, (__bf16)f.y, (__bf16)f.z, (__bf16)f.w};
    reinterpret_cast<bf16x4*>(dst)[i] = h;
  } else if (b < 5136) {
    int t = b - 5120;
    int bx = t & 3, by = t >> 2;
    int r0 = tid >> 6, col = tid & 63;
#pragma unroll
    for (int it = 0; it < 16; ++it) {
      int row = it * 4 + r0;
      s[row][col] = mem[(size_t)(by * 64 + row) * DMEM + bx * 64 + col];
    }
    __syncthreads();
#pragma unroll
    for (int it = 0; it < 16; ++it) {
      int row = it * 4 + r0;
      memT[(size_t)(bx * 64 + row) * DMEM + by * 64 + col] = (__bf16)s[col][row];
    }
  } else {  // FULL seed: 64 blocks x 256 thr x float4 = 65536 floats
    int g = (b - 5136) * 256 + tid;
    reinterpret_cast<float4*>(out + (size_t)MTOT * HIDDEN)[g] =
        reinterpret_cast<const float4*>(mem)[g];
  }
}

// ---------------- K1: fused QKV projection, 64x128 BK=64, grid (64,6) ----------------
__global__ __launch_bounds__(256) void k1_qkv_mfma(
    const __bf16* __restrict__ X, const __bf16* __restrict__ W, __bf16* __restrict__ sqb,
    __bf16* __restrict__ skb, __bf16* __restrict__ skT, __bf16* __restrict__ vT) {
  __shared__ __bf16 As[4096];
  __shared__ __bf16 Bs[8192];
  int tid = threadIdx.x;
  int lane = tid & 63, wave = tid >> 6;
  int m0 = blockIdx.x * 64;
  int by = blockIdx.y;
  int wsel = by >> 1, n0 = (by & 1) * 128;
  const __bf16* aptr = X + (size_t)(m0 + (tid >> 2)) * HIDDEN + ((tid & 3) << 3);
  const __bf16* bptr = W + (size_t)(by * 128 + (tid >> 2)) * HIDDEN + ((tid & 3) << 3);
  int wr = wave >> 1, wc = wave & 1, quad = lane >> 4, l16 = lane & 15;
  f32x4 acc[2][4] = {};
  gemm64_bk64(aptr, bptr, HIDDEN, HIDDEN, As, Bs, wave, wr, wc, quad, l16, acc);
#pragma unroll
  for (int i = 0; i < 2; ++i)
#pragma unroll
    for (int j = 0; j < 4; ++j) {
      int mb = m0 + wr * 32 + i * 16 + quad * 4;
      int n = n0 + wc * 64 + j * 16 + l16;
      if (wsel == 0) {
#pragma unroll
        for (int r = 0; r < 4; ++r) sqb[(size_t)(mb + r) * DMEM + n] = (__bf16)elu1(acc[i][j][r]);
      } else if (wsel == 1) {
        bf16x4 t;
#pragma unroll
        for (int r = 0; r < 4; ++r) {
          float v = elu1(acc[i][j][r]);
          skb[(size_t)(mb + r) * DMEM + n] = (__bf16)v;
          t[r] = (__bf16)v;
        }
        *reinterpret_cast<bf16x4*>(skT + (size_t)n * MTOT + mb) = t;
      } else {
        bf16x4 t;
#pragma unroll
        for (int r = 0; r < 4; ++r) t[r] = (__bf16)acc[i][j][r];
        *reinterpret_cast<bf16x4*>(vT + (size_t)n * MTOT + mb) = t;
      }
    }
}

// ------- kC: chunk-KV 64x128 (y<8) + causal scores (y=8,9) + ksum (y=10). grid (32,11) ------
__global__ __launch_bounds__(256) void kC(const __bf16* __restrict__ vT,
                                          const __bf16* __restrict__ skT,
                                          const __bf16* __restrict__ sqb,
                                          const __bf16* __restrict__ skb,
                                          __bf16* __restrict__ kvcT, __bf16* __restrict__ scb,
                                          float* __restrict__ ksc) {
  __shared__ __bf16 As[4096];
  __shared__ __bf16 Bs[8192];
  int tid = threadIdx.x;
  int c = blockIdx.x;
  int y = blockIdx.y;
  if (y == 10) {
    int d = tid;
    float s = 0.f;
    for (int i = 0; i < CHUNK; ++i) s += (float)skb[(size_t)(c * CHUNK + i) * DMEM + d];
    ksc[c * DMEM + d] = s;
    return;
  }
  int lane = tid & 63, wave = tid >> 6;
  int wr = wave >> 1, wc = wave & 1, quad = lane >> 4, l16 = lane & 15;
  if (y < 8) {  // kvcT[c][e][d] = sum_s vT[e,s]*skT[d,s], 64x128 tile
    int e0 = (y >> 1) * 64, d0 = (y & 1) * 128;
    const __bf16* aptr = vT + (size_t)(e0 + (tid >> 2)) * MTOT + c * CHUNK + ((tid & 3) << 3);
    const __bf16* bptr = skT + (size_t)(d0 + (tid >> 2)) * MTOT + c * CHUNK + ((tid & 3) << 3);
    f32x4 acc[2][4] = {};
    gemm64_bk64(aptr, bptr, MTOT, CHUNK, As, Bs, wave, wr, wc, quad, l16, acc);
#pragma unroll
    for (int i = 0; i < 2; ++i)
#pragma unroll
      for (int j = 0; j < 4; ++j)
#pragma unroll
        for (int r = 0; r < 4; ++r) {
          int e = e0 + wr * 32 + i * 16 + quad * 4 + r;
          int d = d0 + wc * 64 + j * 16 + l16;
          kvcT[(size_t)c * DMEM * DMEM + (size_t)e * DMEM + d] = (__bf16)acc[i][j][r];
        }
  } else {  // causal scores, i0 = (y-8)*64
    int i0 = (y - 8) * 64;
    const __bf16* aptr = sqb + (size_t)(c * CHUNK + i0 + (tid >> 2)) * DMEM + ((tid & 3) << 3);
    const __bf16* bptr = skb + (size_t)(c * CHUNK + (tid >> 2)) * DMEM + ((tid & 3) << 3);
    f32x4 acc[2][4] = {};
    gemm64_bk64(aptr, bptr, DMEM, DMEM, As, Bs, wave, wr, wc, quad, l16, acc);
#pragma unroll
    for (int i = 0; i < 2; ++i)
#pragma unroll
      for (int j = 0; j < 4; ++j)
#pragma unroll
        for (int r = 0; r < 4; ++r) {
          int ii = i0 + wr * 32 + i * 16 + quad * 4 + r;
          int jj = wc * 64 + j * 16 + l16;
          scb[(size_t)c * CHUNK * CHUNK + (size_t)ii * CHUNK + jj] =
              (jj <= ii) ? (__bf16)acc[i][j][r] : (__bf16)0.f;
        }
  }
}

// ---------------- kD: vectorized prefix (vt<128) + row scalars (vt>=128). grid 1152 -------
__global__ __launch_bounds__(256) void kD(const __bf16* __restrict__ kvcT,
                                          __bf16* __restrict__ kvpT,
                                          const float* __restrict__ ksc,
                                          const __bf16* __restrict__ scb,
                                          const __bf16* __restrict__ sqb,
                                          const __bf16* __restrict__ skb,
                                          const float* __restrict__ mnorm,
                                          float* __restrict__ den, float* __restrict__ qn,
                                          float* __restrict__ kn) {
  int vt = blockIdx.x;
  int tid = threadIdx.x;
  if (vt < 128) {
    int batch = vt >> 5;
    size_t idx8 = (size_t)(((vt & 31) * 256 + tid)) * 8;
    // hoist all 8 chunk loads (independent, issue together), then prefix in regs
    bf16x8 t[NCH];
#pragma unroll
    for (int c = 0; c < NCH; ++c)
      t[c] = *reinterpret_cast<const bf16x8*>(kvcT +
                                              (size_t)(batch * NCH + c) * DMEM * DMEM + idx8);
    float run[8] = {};
#pragma unroll
    for (int c = 0; c < NCH; ++c) {
      bf16x8 o;
#pragma unroll
      for (int r = 0; r < 8; ++r) o[r] = (__bf16)run[r];
      *reinterpret_cast<bf16x8*>(kvpT + (size_t)(batch * NCH + c) * DMEM * DMEM + idx8) = o;
#pragma unroll
      for (int r = 0; r < 8; ++r) run[r] += (float)t[c][r];
    }
  } else {
    int wave = tid >> 6, lane = tid & 63;
    int m = (vt - 128) * 4 + wave;
    int c = m >> 7;
    int i = m & 127;
    int cb = c & ~7;
    int cnt = c - cb;  // 0..7
    float s_sc = 0.f, s_d2 = 0.f, s_qn = 0.f, s_kn = 0.f;
    for (int j = lane; j < CHUNK; j += 64)
      s_sc += (float)scb[(size_t)c * CHUNK * CHUNK + (size_t)i * CHUNK + j];
    for (int d = lane; d < DMEM; d += 64) {
      float q = (float)sqb[(size_t)m * DMEM + d];
      float k = (float)skb[(size_t)m * DMEM + d];
      float kp = 0.f;
      // predicated unroll: 7 independent loads in flight (max idx (24+6)*256+255 < 8192);
      // ascending masked adds keep the fp32 sum bitwise identical to the serial loop.
#pragma unroll
      for (int cc = 0; cc < 7; ++cc) {
        float v = ksc[(cb + cc) * DMEM + d];
        kp += (cc < cnt) ? v : 0.f;
      }
      s_d2 += q * kp;
      s_qn += q * mnorm[d];
      s_kn += k * mnorm[d];
    }
#pragma unroll
    for (int off = 32; off > 0; off >>= 1) {
      s_sc += __shfl_down(s_sc, off);
      s_d2 += __shfl_down(s_d2, off);
      s_qn += __shfl_down(s_qn, off);
      s_kn += __shfl_down(s_kn, off);
    }
    if (lane == 0) {
      den[m] = s_sc + s_d2;
      qn[m] = s_qn;
      kn[m] = s_kn;
    }
  }
}

// ---------------- kE: combine (bid<128) + delta-v (128..255). grid 256 ----------------
__global__ __launch_bounds__(256) void kE(const __bf16* __restrict__ scb,
                                          const __bf16* __restrict__ sqb,
                                          const __bf16* __restrict__ skb,
                                          const __bf16* __restrict__ vT,
                                          const __bf16* __restrict__ kvpT,
                                          const __bf16* __restrict__ memT,
                                          const float* __restrict__ den,
                                          const float* __restrict__ qn,
                                          const float* __restrict__ kn,
                                          const float* __restrict__ gate,
                                          const float* __restrict__ mnorm,
                                          __bf16* __restrict__ combb, __bf16* __restrict__ dvT) {
  __shared__ __bf16 As[4096];
  __shared__ __bf16 B1s[8192];
  __shared__ __bf16 B2s[8192];
  __shared__ float warr[4];
  int tid = threadIdx.x;
  int lane = tid & 63, wave = tid >> 6;
  int wr = wave >> 1, wc = wave & 1, quad = lane >> 4, l16 = lane & 15;
  int bid = blockIdx.x;
  if (bid < 128) {  // combine
    float mv = mnorm[tid];
#pragma unroll
    for (int off = 32; off > 0; off >>= 1) mv += __shfl_down(mv, off);
    if (lane == 0) warr[wave] = mv;
    __syncthreads();
    float fl = ((warr[0] + warr[1] + warr[2] + warr[3]) < EPSF) ? 0.f : 1.f;
    __syncthreads();
    int c = bid >> 2, yy = bid & 3;
    int i0 = (yy >> 1) * 64, e0 = (yy & 1) * 128;
    f32x4 acc_loc[2][4] = {};
    f32x4 acc_mem[2][4] = {};
    {  // phase 1: scores @ v (K=128)
      const __bf16* aptr =
          scb + (size_t)c * CHUNK * CHUNK + (size_t)(i0 + (tid >> 2)) * CHUNK + ((tid & 3) << 3);
      const __bf16* bptr = vT + (size_t)(e0 + (tid >> 2)) * MTOT + c * CHUNK + ((tid & 3) << 3);
      gemm64_bk64(aptr, bptr, MTOT, CHUNK, As, B1s, wave, wr, wc, quad, l16, acc_loc);
    }
    {  // phase 2: sq @ kvp + sq @ memT (K=256, dual B)
      const __bf16* aptr = sqb + (size_t)(c * CHUNK + i0 + (tid >> 2)) * DMEM + ((tid & 3) << 3);
      const __bf16* b1ptr =
          kvpT + (size_t)c * DMEM * DMEM + (size_t)(e0 + (tid >> 2)) * DMEM + ((tid & 3) << 3);
      const __bf16* b2ptr = memT + (size_t)(e0 + (tid >> 2)) * DMEM + ((tid & 3) << 3);
      for (int k0 = 0; k0 < DMEM; k0 += 64) {
        stage64(aptr, k0, As, wave);
        stage128(b1ptr, DMEM, k0, B1s, wave);
        stage128(b2ptr, DMEM, k0, B2s, wave);
        __syncthreads();
#pragma unroll
        for (int h = 0; h < 2; ++h) {
          bf16x8 aF[2], b1F[4], b2F[4];
#pragma unroll
          for (int i = 0; i < 2; ++i)
            aF[i] = *reinterpret_cast<const bf16x8*>(As + h * 2048 +
                                                     (wr * 32 + i * 16 + l16) * 32 + quad * 8);
#pragma unroll
          for (int j = 0; j < 4; ++j) {
            b1F[j] = *reinterpret_cast<const bf16x8*>(B1s + h * 4096 +
                                                      (wc * 64 + j * 16 + l16) * 32 + quad * 8);
            b2F[j] = *reinterpret_cast<const bf16x8*>(B2s + h * 4096 +
                                                      (wc * 64 + j * 16 + l16) * 32 + quad * 8);
          }
#pragma unroll
          for (int i = 0; i < 2; ++i)
#pragma unroll
            for (int j = 0; j < 4; ++j) {
              acc_loc[i][j] =
                  __builtin_amdgcn_mfma_f32_16x16x32_bf16(aF[i], b1F[j], acc_loc[i][j], 0, 0, 0);
              acc_mem[i][j] =
                  __builtin_amdgcn_mfma_f32_16x16x32_bf16(aF[i], b2F[j], acc_mem[i][j], 0, 0, 0);
            }
        }
        __syncthreads();
      }
    }
    float g = 1.f / (1.f + __expf(-gate[0]));
#pragma unroll
    for (int i = 0; i < 2; ++i) {
      int mb = c * CHUNK + i0 + wr * 32 + i * 16 + quad * 4;
      float dn[4], qv[4];
#pragma unroll
      for (int r = 0; r < 4; ++r) {
        dn[r] = fmaxf(den[mb + r], EPSF);
        qv[r] = fmaxf(qn[mb + r], EPSF);
      }
#pragma unroll
      for (int j = 0; j < 4; ++j) {
        int e = e0 + wc * 64 + j * 16 + l16;
#pragma unroll
        for (int r = 0; r < 4; ++r) {
          float comb = g * fl * acc_mem[i][j][r] / qv[r] + (1.f - g) * acc_loc[i][j][r] / dn[r];
          combb[(size_t)(mb + r) * DMEM + e] = (__bf16)comb;
        }
      }
    }
  } else {  // dv = v - (sk@memT)/kn -> dvT, 64x128 tiles
    int t = bid - 128;
    int m0 = (t >> 1) * 64, n0 = (t & 1) * 128;
    const __bf16* aptr = skb + (size_t)(m0 + (tid >> 2)) * DMEM + ((tid & 3) << 3);
    const __bf16* bptr = memT + (size_t)(n0 + (tid >> 2)) * DMEM + ((tid & 3) << 3);
    f32x4 acc[2][4] = {};
    gemm64_bk64(aptr, bptr, DMEM, DMEM, As, B1s, wave, wr, wc, quad, l16, acc);
#pragma unroll
    for (int i = 0; i < 2; ++i) {
      int mb = m0 + wr * 32 + i * 16 + quad * 4;
      float kv[4];
#pragma unroll
      for (int r = 0; r < 4; ++r) kv[r] = fmaxf(kn[mb + r], EPSF);
#pragma unroll
      for (int j = 0; j < 4; ++j) {
        int n = n0 + wc * 64 + j * 16 + l16;
        bf16x4 vv = *reinterpret_cast<const bf16x4*>(vT + (size_t)n * MTOT + mb);
        bf16x4 tt;
#pragma unroll
        for (int r = 0; r < 4; ++r) tt[r] = (__bf16)((float)vv[r] - acc[i][j][r] / kv[r]);
        *reinterpret_cast<bf16x4*>(dvT + (size_t)n * MTOT + mb) = tt;
      }
    }
  }
}

// -- kF: out-proj (bid<256) + mem-update split-K atomics (256..383) + norm (384). grid 385 --
__global__ __launch_bounds__(256) void kF(const __bf16* __restrict__ combb,
                                          const __bf16* __restrict__ wob,
                                          const __bf16* __restrict__ skT,
                                          const __bf16* __restrict__ dvT,
                                          const float* __restrict__ ksc,
                                          const float* __restrict__ mnorm,
                                          float* __restrict__ out) {
  __shared__ __bf16 As[8192];
  __shared__ __bf16 Bs[8192];
  int tid = threadIdx.x;
  int bid = blockIdx.x;
  if (bid == 384) {  // new_memory_norm
    int d = tid;
    float s = 0.f;
    for (int c = 0; c < NCHT; ++c) s += ksc[c * DMEM + d];
    out[(size_t)MTOT * HIDDEN + DMEM * DMEM + d] = mnorm[d] + s * (1.f / (float)BATCH);
    return;
  }
  int lane = tid & 63, wave = tid >> 6;
  int wr = wave >> 1, wc = wave & 1, quad = lane >> 4, l16 = lane & 15;
  if (bid < 256) {  // output projection, 128x128 BK=64
    int m0 = (bid & 31) * 128, by = bid >> 5;
    const __bf16* aptr = combb + (size_t)(m0 + (tid >> 2)) * DMEM + ((tid & 3) << 3);
    const __bf16* bptr = wob + (size_t)(by * 128 + (tid >> 2)) * DMEM + ((tid & 3) << 3);
    f32x4 acc[4][4] = {};
    gemm128_bk64(aptr, DMEM, bptr, DMEM, DMEM, As, Bs, wave, wr, wc, quad, l16, acc);
#pragma unroll
    for (int i = 0; i < 4; ++i)
#pragma unroll
      for (int j = 0; j < 4; ++j)
#pragma unroll
        for (int r = 0; r < 4; ++r) {
          int m = m0 + wr * 64 + i * 16 + quad * 4 + r;
          int n = by * 128 + wc * 64 + j * 16 + l16;
          out[(size_t)m * HIDDEN + n] = acc[i][j][r];
        }
  } else {  // mem-update: 16-way split-K (K=256 each), 64x128 tiles, atomics
    int t = bid - 256;
    int kbase = (t >> 3) * 256;
    int yy = t & 7;
    int d0 = (yy >> 1) * 64, e0 = (yy & 1) * 128;
    const __bf16* aptr = skT + (size_t)(d0 + (tid >> 2)) * MTOT + kbase + ((tid & 3) << 3);
    const __bf16* bptr = dvT + (size_t)(e0 + (tid >> 2)) * MTOT + kbase + ((tid & 3) << 3);
    f32x4 acc[2][4] = {};
    gemm64_bk64(aptr, bptr, MTOT, 256, As, Bs, wave, wr, wc, quad, l16, acc);
    float* base = out + (size_t)MTOT * HIDDEN;
#pragma unroll
    for (int i = 0; i < 2; ++i)
#pragma unroll
      for (int j = 0; j < 4; ++j)
#pragma unroll
        for (int r = 0; r < 4; ++r) {
          int d = d0 + wr * 32 + i * 16 + quad * 4 + r;
          int e = e0 + wc * 64 + j * 16 + l16;
          atomicAdd(&base[(size_t)d * DMEM + e], acc[i][j][r] * (1.f / (float)MTOT));
        }
  }
}

extern "C" void kernel_launch(void* const* d_in, const int* in_sizes, int n_in,
                              void* d_out, int out_size, void* d_ws, size_t ws_size,
                              hipStream_t stream) {
  const float* hs = (const float*)d_in[0];
  const float* wq = (const float*)d_in[1];
  const float* wk = (const float*)d_in[2];
  const float* wv = (const float*)d_in[3];
  const float* wo = (const float*)d_in[4];
  const float* gate = (const float*)d_in[5];
  const float* mem = (const float*)d_in[6];
  const float* mnorm = (const float*)d_in[7];
  float* out = (float*)d_out;
  float* ws = (float*)d_ws;

  // fp32 region
  float* ksc = ws;          // 8192
  float* den = ksc + 8192;  // 4096
  float* qn = den + 4096;   // 4096
  float* kn = qn + 4096;    // 4096 (end 20480 floats)
  // bf16 region
  __bf16* kvcT = (__bf16*)(ws + 20480);               // 2097152
  __bf16* hsb = kvcT + (size_t)NCHT * DMEM * DMEM;    // 4194304
  __bf16* wqkvb = hsb + (size_t)MTOT * HIDDEN;        // 786432
  __bf16* wob = wqkvb + (size_t)3 * DMEM * HIDDEN;    // 262144
  __bf16* memT = wob + (size_t)HIDDEN * DMEM;         // 65536
  __bf16* sqb = memT + (size_t)DMEM * DMEM;           // 1048576
  __bf16* skb = sqb + (size_t)MTOT * DMEM;            // 1048576
  __bf16* skT = skb + (size_t)MTOT * DMEM;            // 1048576
  __bf16* vT = skT + (size_t)MTOT * DMEM;             // 1048576
  __bf16* scb = vT + (size_t)MTOT * DMEM;             // 524288
  __bf16* kvpT = scb + (size_t)NCHT * CHUNK * CHUNK;  // 2097152
  __bf16* combb = kvpT + (size_t)NCHT * DMEM * DMEM;  // 1048576
  __bf16* dvT = combb + (size_t)MTOT * DMEM;          // 1048576

  kprep<<<dim3(5200), 256, 0, stream>>>(hs, wq, wk, wv, wo, mem, hsb, wqkvb, wob, memT, out);
  k1_qkv_mfma<<<dim3(64, 6), 256, 0, stream>>>(hsb, wqkvb, sqb, skb, skT, vT);
  kC<<<dim3(NCHT, 11), 256, 0, stream>>>(vT, skT, sqb, skb, kvcT, scb, ksc);
  kD<<<dim3(1152), 256, 0, stream>>>(kvcT, kvpT, ksc, scb, sqb, skb, mnorm, den, qn, kn);
  kE<<<dim3(256), 256, 0, stream>>>(scb, sqb, skb, vT, kvpT, memT, den, qn, kn, gate, mnorm,
                                    combb, dvT);
  kF<<<dim3(385), 256, 0, stream>>>(combb, wob, skT, dvT, ksc, mnorm, out);
}